// Round 6
// baseline (305.433 us; speedup 1.0000x reference)
//
#include <hip/hip_runtime.h>
#include <math.h>

#define B_ 8
#define S_ 4096
#define D_ 1024
#define N_ 64
#define SHIFT_ 2048
#define LCH 32
#define CCH 128            // S_/LCH
#define MTOT (B_*S_)
#define EPS_ 1e-5f

typedef __attribute__((ext_vector_type(8))) short v8s;
typedef __attribute__((ext_vector_type(4))) float v4f;

static __device__ __forceinline__ short f2bf(float f) {
    // round-to-nearest-even fp32 -> bf16
    unsigned int u = __float_as_uint(f);
    u += 0x7fffu + ((u >> 16) & 1u);
    return (short)(u >> 16);
}

// async global->LDS, 16B per lane; LDS dest is wave-uniform base + lane*16
static __device__ __forceinline__ void gl_lds16(const void* g, void* l) {
    __builtin_amdgcn_global_load_lds(
        (const __attribute__((address_space(1))) unsigned int*)g,
        (__attribute__((address_space(3))) unsigned int*)l,
        16, 0, 0);
}

// ---------------- k_conv: weights->bf16, exp(tf), sigmoid(gates) ----------
__global__ __launch_bounds__(256) void k_conv(
    const float* __restrict__ keyw, const float* __restrict__ valw,
    const float* __restrict__ ow, const float* __restrict__ tf,
    const float* __restrict__ tsg,
    short* __restrict__ wbf, short* __restrict__ owbf,
    float* __restrict__ etf, float* __restrict__ g) {
    int i = blockIdx.x * 256 + threadIdx.x;
    if (i < 65536)          wbf[i] = f2bf(keyw[i]);
    else if (i < 131072)    wbf[i] = f2bf(valw[i - 65536]);
    else if (i < 196608)    owbf[i - 131072] = f2bf(ow[i - 131072]);
    else if (i < 196672)    etf[i - 196608] = __expf(tf[i - 196608]);
    else if (i < 197696) {
        int j = i - 196672;
        g[j] = 1.0f / (1.0f + __expf(-tsg[j]));
    }
}

// ---------------- PRIMARY: shift + full LN -> bf16 x_norm ------------------
// One WAVE per token-pair: no LDS, no barriers; 16 elems/thread (4x float4)
// -> 4x loads-in-flight/thread, butterfly shfl_xor gives stats to all lanes.
// Provably race-free: pure dataflow, each output cell written by one thread.
// (byte-identical to round-5 replay-proven version)
__global__ __launch_bounds__(256) void k_stats_fused(
    const float* __restrict__ x, const float* __restrict__ g,
    const float* __restrict__ lnw, const float* __restrict__ lnb,
    short* __restrict__ xn) {
    int wv = threadIdx.x >> 6, lane = threadIdx.x & 63;
    int p = blockIdx.x * 4 + wv;           // pair index 0..16383
    int b = p >> 11;
    int t = p & 2047;
    const float* rowa = x + ((size_t)(b * S_ + t)) * D_;
    const float* rowb = rowa + (size_t)SHIFT_ * D_;
    int c = lane * 16;
    float u[16], w2[16];
    float s1 = 0.f, q1 = 0.f, s2 = 0.f, q2 = 0.f;
#pragma unroll
    for (int q = 0; q < 4; q++) {
        float4 xa = *(const float4*)(rowa + c + q * 4);
        float4 xb = *(const float4*)(rowb + c + q * 4);
        float4 gg = *(const float4*)(g + c + q * 4);
        float xav[4] = {xa.x, xa.y, xa.z, xa.w};
        float xbv[4] = {xb.x, xb.y, xb.z, xb.w};
        float gv4[4] = {gg.x, gg.y, gg.z, gg.w};
#pragma unroll
        for (int j = 0; j < 4; j++) {
            int k = q * 4 + j;
            u[k]  = gv4[j] * xbv[j] + (1.f - gv4[j]) * xav[j];   // token t
            w2[k] = gv4[j] * xav[j] + (1.f - gv4[j]) * xbv[j];   // token t+2048
            s1 += u[k];  q1 += u[k] * u[k];
            s2 += w2[k]; q2 += w2[k] * w2[k];
        }
    }
#pragma unroll
    for (int off = 32; off > 0; off >>= 1) {
        s1 += __shfl_xor(s1, off);
        q1 += __shfl_xor(q1, off);
        s2 += __shfl_xor(s2, off);
        q2 += __shfl_xor(q2, off);
    }
    float m1 = s1 * (1.f / D_), m2 = s2 * (1.f / D_);
    float rs1 = rsqrtf(q1 * (1.f / D_) - m1 * m1 + EPS_);
    float rs2 = rsqrtf(q2 * (1.f / D_) - m2 * m2 + EPS_);
    v8s o1v[2], o2v[2];
#pragma unroll
    for (int q = 0; q < 4; q++) {
        float4 lw = *(const float4*)(lnw + c + q * 4);
        float4 lb = *(const float4*)(lnb + c + q * 4);
        float lwv[4] = {lw.x, lw.y, lw.z, lw.w};
        float lbv[4] = {lb.x, lb.y, lb.z, lb.w};
#pragma unroll
        for (int j = 0; j < 4; j++) {
            int k = q * 4 + j;
            o1v[k >> 3][k & 7] = f2bf((u[k]  - m1) * rs1 * lwv[j] + lbv[j]);
            o2v[k >> 3][k & 7] = f2bf((w2[k] - m2) * rs2 * lwv[j] + lbv[j]);
        }
    }
    short* d1 = xn + ((size_t)(b * S_ + t)) * D_ + c;
    short* d2 = d1 + (size_t)SHIFT_ * D_;
    *(v8s*)d1 = o1v[0];
    *(v8s*)(d1 + 8) = o1v[1];
    *(v8s*)d2 = o2v[0];
    *(v8s*)(d2 + 8) = o2v[1];
}

// ---------------- PRIMARY: MFMA K/V projection (LDS double-buffered) --------
// C[64 tok][128 outs] = xnorm(64x1024) @ wbf^T
// m97 structure: 256 thr / 4 waves, BK=64, global_load_lds(16B) staging into
// XOR-swizzled LDS (linear dest + inverse-swizzled SOURCE + swizzled READ),
// 2-barrier double-buffered K-loop. Epilogue: wkv + fused per-chunk scan.
// (byte-identical to round-2/5 replay-proven version)
__global__ __launch_bounds__(256) void k_proj_mx(
    const short* __restrict__ xn, const short* __restrict__ wbf,
    const float* __restrict__ etf, const float* __restrict__ tdec,
    float* __restrict__ wkv, float* __restrict__ Acar) {
    __shared__ __align__(16) char lds[49152];
    char* Ab = lds;                  // [2][8192] bytes
    char* Bb = lds + 16384;          // [2][16384] bytes
    float* C = (float*)lds;          // epilogue view, 64*132*4 = 33792 B

    int tid = threadIdx.x, wid = tid >> 6, lane = tid & 63;
    int wm = wid >> 1, wn = wid & 1;
    int quad = lane >> 4, l15 = lane & 15;
    int m0 = blockIdx.x * 64;

    const char* xb = (const char*)(xn + (size_t)m0 * D_);
    const char* wb = (const char*)wbf;

    v4f acc[2][4];
#pragma unroll
    for (int i = 0; i < 2; i++)
#pragma unroll
        for (int j = 0; j < 4; j++) acc[i][j] = (v4f)0.f;

    auto stage = [&](int buf, int k0) {
#pragma unroll
        for (int j = 0; j < 2; ++j) {
            int s = j * 256 + wid * 64 + lane;     // 16B slot 0..511
            int r = s >> 3, cu = s & 7;
            gl_lds16(xb + (size_t)r * 2048 + k0 * 2 + ((cu ^ (r & 7)) << 4),
                     Ab + buf * 8192 + (j * 256 + wid * 64) * 16);
        }
#pragma unroll
        for (int j = 0; j < 4; ++j) {
            int s = j * 256 + wid * 64 + lane;     // 16B slot 0..1023
            int r = s >> 3, cu = s & 7;
            gl_lds16(wb + (size_t)r * 2048 + k0 * 2 + ((cu ^ (r & 7)) << 4),
                     Bb + buf * 16384 + (j * 256 + wid * 64) * 16);
        }
    };
    auto ldA = [&](int buf, int r, int cu) -> v8s {
        return *(const v8s*)(Ab + buf * 8192 + r * 128 + ((cu ^ (r & 7)) << 4));
    };
    auto ldB = [&](int buf, int r, int cu) -> v8s {
        return *(const v8s*)(Bb + buf * 16384 + r * 128 + ((cu ^ (r & 7)) << 4));
    };

    stage(0, 0);
    int cur = 0;
    for (int kt = 0; kt < 16; ++kt) {
        __syncthreads();                       // drains vmcnt: buf[cur] ready
        if (kt < 15) stage(cur ^ 1, (kt + 1) * 64);
#pragma unroll
        for (int kk2 = 0; kk2 < 2; ++kk2) {
            int cu = kk2 * 4 + quad;
            v8s a0 = ldA(cur, wm * 32 + l15, cu);
            v8s a1 = ldA(cur, wm * 32 + 16 + l15, cu);
            v8s b0 = ldB(cur, wn * 64 + l15, cu);
            v8s b1 = ldB(cur, wn * 64 + 16 + l15, cu);
            v8s b2 = ldB(cur, wn * 64 + 32 + l15, cu);
            v8s b3 = ldB(cur, wn * 64 + 48 + l15, cu);
            acc[0][0] = __builtin_amdgcn_mfma_f32_16x16x32_bf16(a0, b0, acc[0][0], 0, 0, 0);
            acc[0][1] = __builtin_amdgcn_mfma_f32_16x16x32_bf16(a0, b1, acc[0][1], 0, 0, 0);
            acc[0][2] = __builtin_amdgcn_mfma_f32_16x16x32_bf16(a0, b2, acc[0][2], 0, 0, 0);
            acc[0][3] = __builtin_amdgcn_mfma_f32_16x16x32_bf16(a0, b3, acc[0][3], 0, 0, 0);
            acc[1][0] = __builtin_amdgcn_mfma_f32_16x16x32_bf16(a1, b0, acc[1][0], 0, 0, 0);
            acc[1][1] = __builtin_amdgcn_mfma_f32_16x16x32_bf16(a1, b1, acc[1][1], 0, 0, 0);
            acc[1][2] = __builtin_amdgcn_mfma_f32_16x16x32_bf16(a1, b2, acc[1][2], 0, 0, 0);
            acc[1][3] = __builtin_amdgcn_mfma_f32_16x16x32_bf16(a1, b3, acc[1][3], 0, 0, 0);
        }
        cur ^= 1;
    }
    __syncthreads();   // all ds_reads done -> safe to overwrite LDS with C

    // C/D layout: col = lane&15, row = quad*4 + reg (proven mapping)
#pragma unroll
    for (int i = 0; i < 2; i++)
#pragma unroll
        for (int j = 0; j < 4; j++)
#pragma unroll
            for (int r = 0; r < 4; r++)
                C[(wm * 32 + i * 16 + quad * 4 + r) * 132 + wn * 64 + j * 16 + l15] = acc[i][j][r];
    __syncthreads();

    // wkv epilogue: tok = tid>>2 (0..63), 16 n's per thread
    int tok = tid >> 2, n0 = (tid & 3) * 16;
    float* orow = wkv + ((size_t)(m0 + tok)) * N_ + n0;
    float os[16];
#pragma unroll
    for (int jj = 0; jj < 16; jj++) {
        float kv = C[tok * 132 + n0 + jj];
        float vv = C[tok * 132 + 64 + n0 + jj];
        os[jj] = __expf(-etf[n0 + jj] * kv) * vv;
    }
#pragma unroll
    for (int jj = 0; jj < 16; jj += 4)
        *(float4*)(orow + jj) = make_float4(os[jj], os[jj + 1], os[jj + 2], os[jj + 3]);
    // stash wkv into k-region of C for the in-block chunk scan
    // (each thread overwrites only cells it alone read above -> no hazard)
#pragma unroll
    for (int jj = 0; jj < 16; jj++) C[tok * 132 + n0 + jj] = os[jj];
    __syncthreads();

    // chunk scan: 2 chunks of 32 tokens per block, 64 n's each -> 128 threads
    if (tid < 128) {
        int c = tid >> 6, n = tid & 63;
        float w = expf(tdec[n]);          // match k_chunk/k_rescan precision
        float s = 0.f;
#pragma unroll
        for (int i = 0; i < LCH; i++) s = s * w + C[(c * 32 + i) * 132 + n];
        Acar[((size_t)blockIdx.x * 2 + c) * N_ + n] = s;
    }
}

// ---------------- FALLBACK: LN stats only ----------------------------------
__global__ __launch_bounds__(256) void k_stats_mu(const float* __restrict__ x,
                                                  const float* __restrict__ g,
                                                  float* __restrict__ mu,
                                                  float* __restrict__ rstd) {
    int b = blockIdx.x >> 11;
    int t = blockIdx.x & 2047;
    const float* rowa = x + ((size_t)(b * S_ + t)) * D_;
    const float* rowb = rowa + (size_t)SHIFT_ * D_;
    int c = threadIdx.x * 4;
    float4 xa = *(const float4*)(rowa + c);
    float4 xb = *(const float4*)(rowb + c);
    float4 gg = *(const float4*)(g + c);
    float av[4] = {xa.x, xa.y, xa.z, xa.w};
    float bv[4] = {xb.x, xb.y, xb.z, xb.w};
    float gv[4] = {gg.x, gg.y, gg.z, gg.w};
    float s1 = 0.f, q1 = 0.f, s2 = 0.f, q2 = 0.f;
#pragma unroll
    for (int j = 0; j < 4; j++) {
        float u  = gv[j] * bv[j] + (1.f - gv[j]) * av[j];
        float w2 = gv[j] * av[j] + (1.f - gv[j]) * bv[j];
        s1 += u;  q1 += u * u;
        s2 += w2; q2 += w2 * w2;
    }
    __shared__ float red[4][4];
    int lane = threadIdx.x & 63, wv = threadIdx.x >> 6;
#pragma unroll
    for (int off = 32; off > 0; off >>= 1) {
        s1 += __shfl_down(s1, off);
        q1 += __shfl_down(q1, off);
        s2 += __shfl_down(s2, off);
        q2 += __shfl_down(q2, off);
    }
    if (lane == 0) { red[wv][0] = s1; red[wv][1] = q1; red[wv][2] = s2; red[wv][3] = q2; }
    __syncthreads();
    if (threadIdx.x == 0) {
        float S1 = 0, Q1 = 0, S2 = 0, Q2 = 0;
#pragma unroll
        for (int i = 0; i < 4; i++) { S1 += red[i][0]; Q1 += red[i][1]; S2 += red[i][2]; Q2 += red[i][3]; }
        float m1 = S1 * (1.f / D_), m2 = S2 * (1.f / D_);
        float v1 = Q1 * (1.f / D_) - m1 * m1;
        float v2 = Q2 * (1.f / D_) - m2 * m2;
        int m = b * S_ + t;
        mu[m] = m1;           rstd[m] = rsqrtf(v1 + EPS_);
        mu[m + SHIFT_] = m2;  rstd[m + SHIFT_] = rsqrtf(v2 + EPS_);
    }
}

// ---------------- FALLBACK: fp32 fused projection (round-1, proven) --------
__global__ __launch_bounds__(256) void k_proj_fp32(
    const float* __restrict__ x, const float* __restrict__ keyw,
    const float* __restrict__ valw, const float* __restrict__ g,
    const float* __restrict__ lnw, const float* __restrict__ lnb,
    const float* __restrict__ tf, const float* __restrict__ mu,
    const float* __restrict__ rstd, float* __restrict__ wkv) {
    __shared__ float smem[64 * 132];
    float* As = smem;
    float* Bs = smem + 64 * 36;

    int m0 = blockIdx.x * 64;
    int b = m0 >> 12;
    int t0 = m0 & 4095;
    int t2 = (t0 + SHIFT_) & 4095;
    const float* xa_base = x + ((size_t)(b * S_ + t0)) * D_;
    const float* xb_base = x + ((size_t)(b * S_ + t2)) * D_;

    int tid = threadIdx.x;
    int ty = tid >> 4, tx = tid & 15;
    int tokA = tid >> 3;
    int cA = (tid & 7) * 4;

    float mu0 = mu[m0 + tokA],      rs0 = rstd[m0 + tokA];
    float mu1 = mu[m0 + tokA + 32], rs1 = rstd[m0 + tokA + 32];

    int nB = tid >> 1;
    int halfB = tid & 1;
    const float* wrow = (nB < 64) ? (keyw + (size_t)nB * D_)
                                  : (valw + (size_t)(nB - 64) * D_);

    float acc[4][8];
#pragma unroll
    for (int i = 0; i < 4; i++)
#pragma unroll
        for (int j = 0; j < 8; j++) acc[i][j] = 0.f;

    for (int kk0 = 0; kk0 < D_; kk0 += 32) {
        float4 gg = *(const float4*)(g + kk0 + cA);
        float4 lw = *(const float4*)(lnw + kk0 + cA);
        float4 lb = *(const float4*)(lnb + kk0 + cA);
        float gv[4] = {gg.x, gg.y, gg.z, gg.w};
        float lwv[4] = {lw.x, lw.y, lw.z, lw.w};
        float lbv[4] = {lb.x, lb.y, lb.z, lb.w};
#pragma unroll
        for (int r = 0; r < 2; r++) {
            int tok = tokA + r * 32;
            float4 xa = *(const float4*)(xa_base + (size_t)tok * D_ + kk0 + cA);
            float4 xb = *(const float4*)(xb_base + (size_t)tok * D_ + kk0 + cA);
            float xav[4] = {xa.x, xa.y, xa.z, xa.w};
            float xbv[4] = {xb.x, xb.y, xb.z, xb.w};
            float m_ = r ? mu1 : mu0;
            float rs_ = r ? rs1 : rs0;
#pragma unroll
            for (int j = 0; j < 4; j++) {
                float xs = gv[j] * xbv[j] + (1.f - gv[j]) * xav[j];
                As[tok * 36 + cA + j] = (xs - m_) * rs_ * lwv[j] + lbv[j];
            }
        }
#pragma unroll
        for (int cc = 0; cc < 16; cc += 4) {
            int kk = halfB * 16 + cc;
            float4 wv4 = *(const float4*)(wrow + kk0 + kk);
            Bs[(kk + 0) * 132 + nB] = wv4.x;
            Bs[(kk + 1) * 132 + nB] = wv4.y;
            Bs[(kk + 2) * 132 + nB] = wv4.z;
            Bs[(kk + 3) * 132 + nB] = wv4.w;
        }
        __syncthreads();
#pragma unroll
        for (int kk = 0; kk < 32; kk++) {
            float a0 = As[(ty * 4 + 0) * 36 + kk];
            float a1 = As[(ty * 4 + 1) * 36 + kk];
            float a2 = As[(ty * 4 + 2) * 36 + kk];
            float a3 = As[(ty * 4 + 3) * 36 + kk];
            float bvv[8];
#pragma unroll
            for (int j = 0; j < 8; j++) bvv[j] = Bs[kk * 132 + tx * 8 + j];
#pragma unroll
            for (int j = 0; j < 8; j++) {
                acc[0][j] = fmaf(a0, bvv[j], acc[0][j]);
                acc[1][j] = fmaf(a1, bvv[j], acc[1][j]);
                acc[2][j] = fmaf(a2, bvv[j], acc[2][j]);
                acc[3][j] = fmaf(a3, bvv[j], acc[3][j]);
            }
        }
        __syncthreads();
    }
#pragma unroll
    for (int i = 0; i < 4; i++)
#pragma unroll
        for (int j = 0; j < 8; j++)
            smem[(ty * 4 + i) * 132 + tx * 8 + j] = acc[i][j];
    __syncthreads();
    {
        int tok = tid >> 2;
        int n0 = (tid & 3) * 16;
        float* orow = wkv + ((size_t)(m0 + tok)) * N_ + n0;
#pragma unroll
        for (int jj = 0; jj < 16; jj++) {
            int n = n0 + jj;
            float kv = smem[tok * 132 + n];
            float vv = smem[tok * 132 + 64 + n];
            orow[jj] = __expf(-__expf(tf[n]) * kv) * vv;
        }
    }
}

// ---------------- scan: per-chunk local -> carries (FALLBACK path only) -----
__global__ __launch_bounds__(64) void k_chunk(const float* __restrict__ wkv,
                                              const float* __restrict__ tdec,
                                              float* __restrict__ Acar) {
    int idx = blockIdx.x;
    int n = threadIdx.x;
    float w = expf(tdec[n]);
    const float* p = wkv + (size_t)idx * (LCH * N_) + n;
    float s = 0.f;
#pragma unroll
    for (int i = 0; i < LCH; i++) s = s * w + p[i * N_];
    Acar[idx * N_ + n] = s;
}

// ---------------- scan: carries across chunks; write last_states -----------
__global__ __launch_bounds__(64) void k_carry(const float* __restrict__ Acar,
                                              const float* __restrict__ tdec,
                                              float* __restrict__ Cin,
                                              float* __restrict__ last) {
    int b = blockIdx.x;
    int n = threadIdx.x;
    float wL = expf(tdec[n] * (float)LCH);
    float c = 0.f;
#pragma unroll 16
    for (int ch = 0; ch < CCH; ch++) {
        Cin[(b * CCH + ch) * N_ + n] = c;
        c = c * wL + Acar[(b * CCH + ch) * N_ + n];
    }
    last[b * N_ + n] = c;
}

// ---------------- scan: rescan with carry-in -> bf16 states -----------------
__global__ __launch_bounds__(64) void k_rescan(const float* __restrict__ wkv,
                                               const float* __restrict__ Cin,
                                               const float* __restrict__ tdec,
                                               short* __restrict__ st) {
    int idx = blockIdx.x;
    int n = threadIdx.x;
    float w = expf(tdec[n]);
    float s = Cin[idx * N_ + n];
    const float* p = wkv + (size_t)idx * (LCH * N_) + n;
    short* q = st + (size_t)idx * (LCH * N_) + n;
#pragma unroll
    for (int i = 0; i < LCH; i++) { s = s * w + p[i * N_]; q[i * N_] = f2bf(s); }
}

// ---------------- output projection: A-frags in regs, d-loop inside ---------
// out[m][d] = sum_n st[m][n] * ow[d][n];  per block: 64 m x 512 d (4 tiles)
// grid 1024 = exactly 4 blocks/CU (LDS limit); A loaded once (was 8x);
// stores stream 128 KB/block. Barrier protocol per tile:
//   MFMA -> sync(prev C-reads done) -> write C -> sync(C ready) -> read/store
__global__ __launch_bounds__(256) void k_out_mx(const short* __restrict__ st,
                                                const short* __restrict__ owbf,
                                                float* __restrict__ out) {
    __shared__ float C[64 * 132];   // 33.8 KB
    int tid = threadIdx.x, wid = tid >> 6, lane = tid & 63;
    int wm = wid >> 1, wn = wid & 1;
    int quad = lane >> 4, l15 = lane & 15;
    int m0 = (blockIdx.x >> 1) * 64;
    int dh = blockIdx.x & 1;              // d-half: 0 -> d 0..511, 1 -> 512..1023
    const short* ab = st + ((size_t)(m0 + wm * 32 + l15)) * N_ + quad * 8;
    // A fragments once into registers (reused across 4 d tiles)
    v8s a[2][2];
#pragma unroll
    for (int i = 0; i < 2; i++)
#pragma unroll
        for (int ks = 0; ks < 2; ks++)
            a[i][ks] = *(const v8s*)(ab + i * 16 * N_ + ks * 32);

    int rrow = tid >> 3;
    int ccol = (tid & 7) * 4;

    for (int dt = 0; dt < 4; ++dt) {
        int d0 = (dh * 4 + dt) * 128;
        const short* bb = owbf + ((size_t)(d0 + wn * 64 + l15)) * N_ + quad * 8;
        v4f acc[2][4];
#pragma unroll
        for (int i = 0; i < 2; i++)
#pragma unroll
            for (int j = 0; j < 4; j++) acc[i][j] = (v4f)0.f;
#pragma unroll
        for (int ks = 0; ks < 2; ks++) {
            v8s b0 = *(const v8s*)(bb + ks * 32);
            v8s b1 = *(const v8s*)(bb + 16 * N_ + ks * 32);
            v8s b2 = *(const v8s*)(bb + 32 * N_ + ks * 32);
            v8s b3 = *(const v8s*)(bb + 48 * N_ + ks * 32);
            acc[0][0] = __builtin_amdgcn_mfma_f32_16x16x32_bf16(a[0][ks], b0, acc[0][0], 0, 0, 0);
            acc[0][1] = __builtin_amdgcn_mfma_f32_16x16x32_bf16(a[0][ks], b1, acc[0][1], 0, 0, 0);
            acc[0][2] = __builtin_amdgcn_mfma_f32_16x16x32_bf16(a[0][ks], b2, acc[0][2], 0, 0, 0);
            acc[0][3] = __builtin_amdgcn_mfma_f32_16x16x32_bf16(a[0][ks], b3, acc[0][3], 0, 0, 0);
            acc[1][0] = __builtin_amdgcn_mfma_f32_16x16x32_bf16(a[1][ks], b0, acc[1][0], 0, 0, 0);
            acc[1][1] = __builtin_amdgcn_mfma_f32_16x16x32_bf16(a[1][ks], b1, acc[1][1], 0, 0, 0);
            acc[1][2] = __builtin_amdgcn_mfma_f32_16x16x32_bf16(a[1][ks], b2, acc[1][2], 0, 0, 0);
            acc[1][3] = __builtin_amdgcn_mfma_f32_16x16x32_bf16(a[1][ks], b3, acc[1][3], 0, 0, 0);
        }
        __syncthreads();   // previous iteration's C-reads complete on ALL threads
        // stash C in LDS (same proven layout)
#pragma unroll
        for (int i = 0; i < 2; i++)
#pragma unroll
            for (int j = 0; j < 4; j++)
#pragma unroll
                for (int r = 0; r < 4; r++)
                    C[(wm * 32 + i * 16 + quad * 4 + r) * 132 + wn * 64 + j * 16 + l15] = acc[i][j][r];
        __syncthreads();   // C fully written
        // coalesced stores: 8 lanes cover one row's 128B segment per instruction
#pragma unroll
        for (int rep = 0; rep < 2; rep++) {
            int row = rep * 32 + rrow;
            float* orow = out + ((size_t)(m0 + row)) * D_ + d0;
            const float* crow = &C[row * 132];
#pragma unroll
            for (int k = 0; k < 4; k++) {
                int col = ccol + k * 32;
                *(float4*)(orow + col) = *(const float4*)(crow + col);
            }
        }
    }
}

extern "C" void kernel_launch(void* const* d_in, const int* in_sizes, int n_in,
                              void* d_out, int out_size, void* d_ws, size_t ws_size,
                              hipStream_t stream) {
    const float* x    = (const float*)d_in[0];
    const float* tdec = (const float*)d_in[1];
    const float* tf   = (const float*)d_in[2];
    const float* keyw = (const float*)d_in[3];
    const float* valw = (const float*)d_in[4];
    const float* ow   = (const float*)d_in[5];
    const float* tsg  = (const float*)d_in[6];
    const float* lnw  = (const float*)d_in[7];
    const float* lnb  = (const float*)d_in[8];
    float* out = (float*)d_out;
    float* ws  = (float*)d_ws;

    // workspace layout (float offsets)
    float* g     = ws;                        // 1024
    float* etf   = g + 1024;                  // 64
    short* wbf   = (short*)(etf + 64);        // 131072 shorts = 65536 floats
    short* owbf  = (short*)(ws + 66624);      // 65536 shorts = 32768 floats
    float* mu    = ws + 99392;                // 32768
    float* rstd  = mu + 32768;                // 32768
    float* wkv   = rstd + 32768;              // 2097152
    float* Acar  = wkv + 2097152;             // 65536
    float* Cin   = Acar + 65536;              // 65536
    short* stbf  = (short*)(Cin + 65536);     // 2097152 shorts = 1048576 floats
    short* xnorm = (short*)(ws + 3441728);    // 33554432 shorts = 16777216 floats
    const size_t NEED_PRIMARY = (size_t)(3441728 + 16777216) * 4;  // ~80.9 MB

    k_conv<<<773, 256, 0, stream>>>(keyw, valw, ow, tf, tsg, wbf, owbf, etf, g);

    if (ws_size >= NEED_PRIMARY) {
        k_stats_fused<<<B_ * (S_ / 2) / 4, 256, 0, stream>>>(x, g, lnw, lnb, xnorm);
        // proj also emits Acar (chunk carries) -> no k_chunk in this path
        k_proj_mx<<<MTOT / 64, 256, 0, stream>>>(xnorm, wbf, etf, tdec, wkv, Acar);
    } else {
        k_stats_mu<<<B_ * (S_ / 2), 256, 0, stream>>>(x, g, mu, rstd);
        k_proj_fp32<<<MTOT / 64, 256, 0, stream>>>(x, keyw, valw, g, lnw, lnb, tf, mu, rstd, wkv);
        k_chunk <<<B_ * CCH, 64, 0, stream>>>(wkv, tdec, Acar);
    }
    k_carry <<<B_, 64, 0, stream>>>(Acar, tdec, Cin, out + (size_t)MTOT * D_);
    k_rescan<<<B_ * CCH, 64, 0, stream>>>(wkv, Cin, tdec, stbf);
    k_out_mx<<<(MTOT / 64) * 2, 256, 0, stream>>>(stbf, owbf, out);
}

// Round 7
// 291.428 us; speedup vs baseline: 1.0481x; 1.0481x over previous
//
#include <hip/hip_runtime.h>
#include <math.h>

#define B_ 8
#define S_ 4096
#define D_ 1024
#define N_ 64
#define SHIFT_ 2048
#define LCH 32
#define CCH 128            // S_/LCH
#define MTOT (B_*S_)
#define EPS_ 1e-5f

typedef __attribute__((ext_vector_type(8))) short v8s;
typedef __attribute__((ext_vector_type(4))) float v4f;

static __device__ __forceinline__ short f2bf(float f) {
    // round-to-nearest-even fp32 -> bf16
    unsigned int u = __float_as_uint(f);
    u += 0x7fffu + ((u >> 16) & 1u);
    return (short)(u >> 16);
}

// async global->LDS, 16B per lane; LDS dest is wave-uniform base + lane*16
static __device__ __forceinline__ void gl_lds16(const void* g, void* l) {
    __builtin_amdgcn_global_load_lds(
        (const __attribute__((address_space(1))) unsigned int*)g,
        (__attribute__((address_space(3))) unsigned int*)l,
        16, 0, 0);
}

// ---------------- k_conv: weights->bf16, exp(tf), sigmoid(gates) ----------
__global__ __launch_bounds__(256) void k_conv(
    const float* __restrict__ keyw, const float* __restrict__ valw,
    const float* __restrict__ ow, const float* __restrict__ tf,
    const float* __restrict__ tsg,
    short* __restrict__ wbf, short* __restrict__ owbf,
    float* __restrict__ etf, float* __restrict__ g) {
    int i = blockIdx.x * 256 + threadIdx.x;
    if (i < 65536)          wbf[i] = f2bf(keyw[i]);
    else if (i < 131072)    wbf[i] = f2bf(valw[i - 65536]);
    else if (i < 196608)    owbf[i - 131072] = f2bf(ow[i - 131072]);
    else if (i < 196672)    etf[i - 196608] = __expf(tf[i - 196608]);
    else if (i < 197696) {
        int j = i - 196672;
        g[j] = 1.0f / (1.0f + __expf(-tsg[j]));
    }
}

// ---------------- PRIMARY: shift + full LN -> bf16 x_norm ------------------
// Round-2 block-per-pair version (measured faster than wave-per-pair:
// 288.9 vs 304.6 total; fully-coalesced float4 per instruction wins).
__global__ __launch_bounds__(256) void k_stats_fused(
    const float* __restrict__ x, const float* __restrict__ g,
    const float* __restrict__ lnw, const float* __restrict__ lnb,
    short* __restrict__ xn) {
    int b = blockIdx.x >> 11;
    int t = blockIdx.x & 2047;
    const float* rowa = x + ((size_t)(b * S_ + t)) * D_;
    const float* rowb = rowa + (size_t)SHIFT_ * D_;
    int c = threadIdx.x * 4;
    float4 xa = *(const float4*)(rowa + c);
    float4 xb = *(const float4*)(rowb + c);
    float4 gg = *(const float4*)(g + c);
    float av[4] = {xa.x, xa.y, xa.z, xa.w};
    float bv[4] = {xb.x, xb.y, xb.z, xb.w};
    float gv[4] = {gg.x, gg.y, gg.z, gg.w};
    float u[4], w2[4];
    float s1 = 0.f, q1 = 0.f, s2 = 0.f, q2 = 0.f;
#pragma unroll
    for (int j = 0; j < 4; j++) {
        u[j]  = gv[j] * bv[j] + (1.f - gv[j]) * av[j];   // token t
        w2[j] = gv[j] * av[j] + (1.f - gv[j]) * bv[j];   // token t+2048
        s1 += u[j];  q1 += u[j] * u[j];
        s2 += w2[j]; q2 += w2[j] * w2[j];
    }
    __shared__ float red[4][4];
    int lane = threadIdx.x & 63, wv = threadIdx.x >> 6;
#pragma unroll
    for (int off = 32; off > 0; off >>= 1) {
        s1 += __shfl_down(s1, off);
        q1 += __shfl_down(q1, off);
        s2 += __shfl_down(s2, off);
        q2 += __shfl_down(q2, off);
    }
    if (lane == 0) { red[wv][0] = s1; red[wv][1] = q1; red[wv][2] = s2; red[wv][3] = q2; }
    __syncthreads();
    float S1 = red[0][0] + red[1][0] + red[2][0] + red[3][0];
    float Q1 = red[0][1] + red[1][1] + red[2][1] + red[3][1];
    float S2 = red[0][2] + red[1][2] + red[2][2] + red[3][2];
    float Q2 = red[0][3] + red[1][3] + red[2][3] + red[3][3];
    float m1 = S1 * (1.f / D_), m2 = S2 * (1.f / D_);
    float rs1 = rsqrtf(Q1 * (1.f / D_) - m1 * m1 + EPS_);
    float rs2 = rsqrtf(Q2 * (1.f / D_) - m2 * m2 + EPS_);
    float4 lw = *(const float4*)(lnw + c);
    float4 lb = *(const float4*)(lnb + c);
    float lwv[4] = {lw.x, lw.y, lw.z, lw.w};
    float lbv[4] = {lb.x, lb.y, lb.z, lb.w};
    short o1[4], o2[4];
#pragma unroll
    for (int j = 0; j < 4; j++) {
        o1[j] = f2bf((u[j]  - m1) * rs1 * lwv[j] + lbv[j]);
        o2[j] = f2bf((w2[j] - m2) * rs2 * lwv[j] + lbv[j]);
    }
    short* d1 = xn + ((size_t)(b * S_ + t)) * D_ + c;
    short* d2 = d1 + (size_t)SHIFT_ * D_;
    *(short4*)d1 = make_short4(o1[0], o1[1], o1[2], o1[3]);
    *(short4*)d2 = make_short4(o2[0], o2[1], o2[2], o2[3]);
}

// ---------------- PRIMARY: MFMA K/V projection (LDS double-buffered) --------
// (byte-identical to round-2/5/6 replay-proven version)
__global__ __launch_bounds__(256) void k_proj_mx(
    const short* __restrict__ xn, const short* __restrict__ wbf,
    const float* __restrict__ etf, const float* __restrict__ tdec,
    float* __restrict__ wkv, float* __restrict__ Acar) {
    __shared__ __align__(16) char lds[49152];
    char* Ab = lds;                  // [2][8192] bytes
    char* Bb = lds + 16384;          // [2][16384] bytes
    float* C = (float*)lds;          // epilogue view, 64*132*4 = 33792 B

    int tid = threadIdx.x, wid = tid >> 6, lane = tid & 63;
    int wm = wid >> 1, wn = wid & 1;
    int quad = lane >> 4, l15 = lane & 15;
    int m0 = blockIdx.x * 64;

    const char* xb = (const char*)(xn + (size_t)m0 * D_);
    const char* wb = (const char*)wbf;

    v4f acc[2][4];
#pragma unroll
    for (int i = 0; i < 2; i++)
#pragma unroll
        for (int j = 0; j < 4; j++) acc[i][j] = (v4f)0.f;

    auto stage = [&](int buf, int k0) {
#pragma unroll
        for (int j = 0; j < 2; ++j) {
            int s = j * 256 + wid * 64 + lane;     // 16B slot 0..511
            int r = s >> 3, cu = s & 7;
            gl_lds16(xb + (size_t)r * 2048 + k0 * 2 + ((cu ^ (r & 7)) << 4),
                     Ab + buf * 8192 + (j * 256 + wid * 64) * 16);
        }
#pragma unroll
        for (int j = 0; j < 4; ++j) {
            int s = j * 256 + wid * 64 + lane;     // 16B slot 0..1023
            int r = s >> 3, cu = s & 7;
            gl_lds16(wb + (size_t)r * 2048 + k0 * 2 + ((cu ^ (r & 7)) << 4),
                     Bb + buf * 16384 + (j * 256 + wid * 64) * 16);
        }
    };
    auto ldA = [&](int buf, int r, int cu) -> v8s {
        return *(const v8s*)(Ab + buf * 8192 + r * 128 + ((cu ^ (r & 7)) << 4));
    };
    auto ldB = [&](int buf, int r, int cu) -> v8s {
        return *(const v8s*)(Bb + buf * 16384 + r * 128 + ((cu ^ (r & 7)) << 4));
    };

    stage(0, 0);
    int cur = 0;
    for (int kt = 0; kt < 16; ++kt) {
        __syncthreads();                       // drains vmcnt: buf[cur] ready
        if (kt < 15) stage(cur ^ 1, (kt + 1) * 64);
#pragma unroll
        for (int kk2 = 0; kk2 < 2; ++kk2) {
            int cu = kk2 * 4 + quad;
            v8s a0 = ldA(cur, wm * 32 + l15, cu);
            v8s a1 = ldA(cur, wm * 32 + 16 + l15, cu);
            v8s b0 = ldB(cur, wn * 64 + l15, cu);
            v8s b1 = ldB(cur, wn * 64 + 16 + l15, cu);
            v8s b2 = ldB(cur, wn * 64 + 32 + l15, cu);
            v8s b3 = ldB(cur, wn * 64 + 48 + l15, cu);
            acc[0][0] = __builtin_amdgcn_mfma_f32_16x16x32_bf16(a0, b0, acc[0][0], 0, 0, 0);
            acc[0][1] = __builtin_amdgcn_mfma_f32_16x16x32_bf16(a0, b1, acc[0][1], 0, 0, 0);
            acc[0][2] = __builtin_amdgcn_mfma_f32_16x16x32_bf16(a0, b2, acc[0][2], 0, 0, 0);
            acc[0][3] = __builtin_amdgcn_mfma_f32_16x16x32_bf16(a0, b3, acc[0][3], 0, 0, 0);
            acc[1][0] = __builtin_amdgcn_mfma_f32_16x16x32_bf16(a1, b0, acc[1][0], 0, 0, 0);
            acc[1][1] = __builtin_amdgcn_mfma_f32_16x16x32_bf16(a1, b1, acc[1][1], 0, 0, 0);
            acc[1][2] = __builtin_amdgcn_mfma_f32_16x16x32_bf16(a1, b2, acc[1][2], 0, 0, 0);
            acc[1][3] = __builtin_amdgcn_mfma_f32_16x16x32_bf16(a1, b3, acc[1][3], 0, 0, 0);
        }
        cur ^= 1;
    }
    __syncthreads();   // all ds_reads done -> safe to overwrite LDS with C

    // C/D layout: col = lane&15, row = quad*4 + reg (proven mapping)
#pragma unroll
    for (int i = 0; i < 2; i++)
#pragma unroll
        for (int j = 0; j < 4; j++)
#pragma unroll
            for (int r = 0; r < 4; r++)
                C[(wm * 32 + i * 16 + quad * 4 + r) * 132 + wn * 64 + j * 16 + l15] = acc[i][j][r];
    __syncthreads();

    // wkv epilogue: tok = tid>>2 (0..63), 16 n's per thread
    int tok = tid >> 2, n0 = (tid & 3) * 16;
    float* orow = wkv + ((size_t)(m0 + tok)) * N_ + n0;
    float os[16];
#pragma unroll
    for (int jj = 0; jj < 16; jj++) {
        float kv = C[tok * 132 + n0 + jj];
        float vv = C[tok * 132 + 64 + n0 + jj];
        os[jj] = __expf(-etf[n0 + jj] * kv) * vv;
    }
#pragma unroll
    for (int jj = 0; jj < 16; jj += 4)
        *(float4*)(orow + jj) = make_float4(os[jj], os[jj + 1], os[jj + 2], os[jj + 3]);
    // stash wkv into k-region of C for the in-block chunk scan
    // (each thread overwrites only cells it alone read above -> no hazard)
#pragma unroll
    for (int jj = 0; jj < 16; jj++) C[tok * 132 + n0 + jj] = os[jj];
    __syncthreads();

    // chunk scan: 2 chunks of 32 tokens per block, 64 n's each -> 128 threads
    if (tid < 128) {
        int c = tid >> 6, n = tid & 63;
        float w = expf(tdec[n]);          // match k_carry/rescan precision
        float s = 0.f;
#pragma unroll
        for (int i = 0; i < LCH; i++) s = s * w + C[(c * 32 + i) * 132 + n];
        Acar[((size_t)blockIdx.x * 2 + c) * N_ + n] = s;
    }
}

// ---------------- FALLBACK: LN stats only ----------------------------------
__global__ __launch_bounds__(256) void k_stats_mu(const float* __restrict__ x,
                                                  const float* __restrict__ g,
                                                  float* __restrict__ mu,
                                                  float* __restrict__ rstd) {
    int b = blockIdx.x >> 11;
    int t = blockIdx.x & 2047;
    const float* rowa = x + ((size_t)(b * S_ + t)) * D_;
    const float* rowb = rowa + (size_t)SHIFT_ * D_;
    int c = threadIdx.x * 4;
    float4 xa = *(const float4*)(rowa + c);
    float4 xb = *(const float4*)(rowb + c);
    float4 gg = *(const float4*)(g + c);
    float av[4] = {xa.x, xa.y, xa.z, xa.w};
    float bv[4] = {xb.x, xb.y, xb.z, xb.w};
    float gv[4] = {gg.x, gg.y, gg.z, gg.w};
    float s1 = 0.f, q1 = 0.f, s2 = 0.f, q2 = 0.f;
#pragma unroll
    for (int j = 0; j < 4; j++) {
        float u  = gv[j] * bv[j] + (1.f - gv[j]) * av[j];
        float w2 = gv[j] * av[j] + (1.f - gv[j]) * bv[j];
        s1 += u;  q1 += u * u;
        s2 += w2; q2 += w2 * w2;
    }
    __shared__ float red[4][4];
    int lane = threadIdx.x & 63, wv = threadIdx.x >> 6;
#pragma unroll
    for (int off = 32; off > 0; off >>= 1) {
        s1 += __shfl_down(s1, off);
        q1 += __shfl_down(q1, off);
        s2 += __shfl_down(s2, off);
        q2 += __shfl_down(q2, off);
    }
    if (lane == 0) { red[wv][0] = s1; red[wv][1] = q1; red[wv][2] = s2; red[wv][3] = q2; }
    __syncthreads();
    if (threadIdx.x == 0) {
        float S1 = 0, Q1 = 0, S2 = 0, Q2 = 0;
#pragma unroll
        for (int i = 0; i < 4; i++) { S1 += red[i][0]; Q1 += red[i][1]; S2 += red[i][2]; Q2 += red[i][3]; }
        float m1 = S1 * (1.f / D_), m2 = S2 * (1.f / D_);
        float v1 = Q1 * (1.f / D_) - m1 * m1;
        float v2 = Q2 * (1.f / D_) - m2 * m2;
        int m = b * S_ + t;
        mu[m] = m1;           rstd[m] = rsqrtf(v1 + EPS_);
        mu[m + SHIFT_] = m2;  rstd[m + SHIFT_] = rsqrtf(v2 + EPS_);
    }
}

// ---------------- FALLBACK: fp32 fused projection (round-1, proven) --------
__global__ __launch_bounds__(256) void k_proj_fp32(
    const float* __restrict__ x, const float* __restrict__ keyw,
    const float* __restrict__ valw, const float* __restrict__ g,
    const float* __restrict__ lnw, const float* __restrict__ lnb,
    const float* __restrict__ tf, const float* __restrict__ mu,
    const float* __restrict__ rstd, float* __restrict__ wkv) {
    __shared__ float smem[64 * 132];
    float* As = smem;
    float* Bs = smem + 64 * 36;

    int m0 = blockIdx.x * 64;
    int b = m0 >> 12;
    int t0 = m0 & 4095;
    int t2 = (t0 + SHIFT_) & 4095;
    const float* xa_base = x + ((size_t)(b * S_ + t0)) * D_;
    const float* xb_base = x + ((size_t)(b * S_ + t2)) * D_;

    int tid = threadIdx.x;
    int ty = tid >> 4, tx = tid & 15;
    int tokA = tid >> 3;
    int cA = (tid & 7) * 4;

    float mu0 = mu[m0 + tokA],      rs0 = rstd[m0 + tokA];
    float mu1 = mu[m0 + tokA + 32], rs1 = rstd[m0 + tokA + 32];

    int nB = tid >> 1;
    int halfB = tid & 1;
    const float* wrow = (nB < 64) ? (keyw + (size_t)nB * D_)
                                  : (valw + (size_t)(nB - 64) * D_);

    float acc[4][8];
#pragma unroll
    for (int i = 0; i < 4; i++)
#pragma unroll
        for (int j = 0; j < 8; j++) acc[i][j] = 0.f;

    for (int kk0 = 0; kk0 < D_; kk0 += 32) {
        float4 gg = *(const float4*)(g + kk0 + cA);
        float4 lw = *(const float4*)(lnw + kk0 + cA);
        float4 lb = *(const float4*)(lnb + kk0 + cA);
        float gv[4] = {gg.x, gg.y, gg.z, gg.w};
        float lwv[4] = {lw.x, lw.y, lw.z, lw.w};
        float lbv[4] = {lb.x, lb.y, lb.z, lb.w};
#pragma unroll
        for (int r = 0; r < 2; r++) {
            int tok = tokA + r * 32;
            float4 xa = *(const float4*)(xa_base + (size_t)tok * D_ + kk0 + cA);
            float4 xb = *(const float4*)(xb_base + (size_t)tok * D_ + kk0 + cA);
            float xav[4] = {xa.x, xa.y, xa.z, xa.w};
            float xbv[4] = {xb.x, xb.y, xb.z, xb.w};
            float m_ = r ? mu1 : mu0;
            float rs_ = r ? rs1 : rs0;
#pragma unroll
            for (int j = 0; j < 4; j++) {
                float xs = gv[j] * xbv[j] + (1.f - gv[j]) * xav[j];
                As[tok * 36 + cA + j] = (xs - m_) * rs_ * lwv[j] + lbv[j];
            }
        }
#pragma unroll
        for (int cc = 0; cc < 16; cc += 4) {
            int kk = halfB * 16 + cc;
            float4 wv4 = *(const float4*)(wrow + kk0 + kk);
            Bs[(kk + 0) * 132 + nB] = wv4.x;
            Bs[(kk + 1) * 132 + nB] = wv4.y;
            Bs[(kk + 2) * 132 + nB] = wv4.z;
            Bs[(kk + 3) * 132 + nB] = wv4.w;
        }
        __syncthreads();
#pragma unroll
        for (int kk = 0; kk < 32; kk++) {
            float a0 = As[(ty * 4 + 0) * 36 + kk];
            float a1 = As[(ty * 4 + 1) * 36 + kk];
            float a2 = As[(ty * 4 + 2) * 36 + kk];
            float a3 = As[(ty * 4 + 3) * 36 + kk];
            float bvv[8];
#pragma unroll
            for (int j = 0; j < 8; j++) bvv[j] = Bs[kk * 132 + tx * 8 + j];
#pragma unroll
            for (int j = 0; j < 8; j++) {
                acc[0][j] = fmaf(a0, bvv[j], acc[0][j]);
                acc[1][j] = fmaf(a1, bvv[j], acc[1][j]);
                acc[2][j] = fmaf(a2, bvv[j], acc[2][j]);
                acc[3][j] = fmaf(a3, bvv[j], acc[3][j]);
            }
        }
        __syncthreads();
    }
#pragma unroll
    for (int i = 0; i < 4; i++)
#pragma unroll
        for (int j = 0; j < 8; j++)
            smem[(ty * 4 + i) * 132 + tx * 8 + j] = acc[i][j];
    __syncthreads();
    {
        int tok = tid >> 2;
        int n0 = (tid & 3) * 16;
        float* orow = wkv + ((size_t)(m0 + tok)) * N_ + n0;
#pragma unroll
        for (int jj = 0; jj < 16; jj++) {
            int n = n0 + jj;
            float kv = smem[tok * 132 + n];
            float vv = smem[tok * 132 + 64 + n];
            orow[jj] = __expf(-__expf(tf[n]) * kv) * vv;
        }
    }
}

// ---------------- scan: per-chunk local -> carries (FALLBACK path only) -----
__global__ __launch_bounds__(64) void k_chunk(const float* __restrict__ wkv,
                                              const float* __restrict__ tdec,
                                              float* __restrict__ Acar) {
    int idx = blockIdx.x;
    int n = threadIdx.x;
    float w = expf(tdec[n]);
    const float* p = wkv + (size_t)idx * (LCH * N_) + n;
    float s = 0.f;
#pragma unroll
    for (int i = 0; i < LCH; i++) s = s * w + p[i * N_];
    Acar[idx * N_ + n] = s;
}

// ---------------- scan: carries across chunks; write last_states -----------
__global__ __launch_bounds__(64) void k_carry(const float* __restrict__ Acar,
                                              const float* __restrict__ tdec,
                                              float* __restrict__ Cin,
                                              float* __restrict__ last) {
    int b = blockIdx.x;
    int n = threadIdx.x;
    float wL = expf(tdec[n] * (float)LCH);
    float c = 0.f;
#pragma unroll 16
    for (int ch = 0; ch < CCH; ch++) {
        Cin[(b * CCH + ch) * N_ + n] = c;
        c = c * wL + Acar[(b * CCH + ch) * N_ + n];
    }
    last[b * N_ + n] = c;
}

// ---------------- output projection, rescan FUSED in -----------------------
// Per block: 64 m x 512 d (dh half). Phase 1: 128 threads rescan this
// block's 2 chunks from wkv+Cin into an XOR-swizzled LDS bf16 tile (both
// dh-halves duplicate this tiny scan -> no stbf global traffic at all).
// Phase 2: A-frags from LDS once into regs, then 4 x {MFMA, C-transpose,
// streamed float4 stores}. LDS st-tile aliases C (st dead after A-load;
// first in-loop barrier orders A-reads before C-writes).
__global__ __launch_bounds__(256) void k_out_mx(const float* __restrict__ wkv,
                                                const float* __restrict__ Cin,
                                                const float* __restrict__ tdec,
                                                const short* __restrict__ owbf,
                                                float* __restrict__ out) {
    __shared__ __align__(16) char smem[64 * 132 * 4];   // 33.8 KB
    char* stl = smem;               // phase-1 view: [64 rows][128 B] swizzled bf16
    float* C = (float*)smem;        // phase-2 view

    int tid = threadIdx.x, wid = tid >> 6, lane = tid & 63;
    int wm = wid >> 1, wn = wid & 1;
    int quad = lane >> 4, l15 = lane & 15;
    int m0 = (blockIdx.x >> 1) * 64;
    int dh = blockIdx.x & 1;        // d-half: 0 -> d 0..511, 1 -> 512..1023

    // ---- phase 1: rescan 2 chunks into swizzled LDS bf16 tile ----
    if (tid < 128) {
        int c = tid >> 6, n = tid & 63;
        int idx = (blockIdx.x >> 1) * 2 + c;           // global chunk index
        float w = expf(tdec[n]);                       // matches k_carry/k_chunk
        float s = Cin[idx * N_ + n];
        const float* p = wkv + (size_t)idx * (LCH * N_) + n;
        int cu = (n * 2) >> 4, off = (n * 2) & 15;     // 16B unit + byte within
#pragma unroll
        for (int i = 0; i < LCH; i++) {
            s = s * w + p[i * N_];
            int row = c * 32 + i;
            *(short*)(stl + row * 128 + ((cu ^ (row & 7)) << 4) + off) = f2bf(s);
        }
    }
    __syncthreads();   // st tile ready

    // ---- A fragments once into registers (swizzled LDS read) ----
    v8s a[2][2];
#pragma unroll
    for (int i = 0; i < 2; i++)
#pragma unroll
        for (int ks = 0; ks < 2; ks++) {
            int row = wm * 32 + i * 16 + l15;
            int cu = quad + ks * 4;                    // col = quad*8 + ks*32 bf16
            a[i][ks] = *(const v8s*)(stl + row * 128 + ((cu ^ (row & 7)) << 4));
        }

    int rrow = tid >> 3;
    int ccol = (tid & 7) * 4;

    for (int dt = 0; dt < 4; ++dt) {
        int d0 = (dh * 4 + dt) * 128;
        const short* bb = owbf + ((size_t)(d0 + wn * 64 + l15)) * N_ + quad * 8;
        v4f acc[2][4];
#pragma unroll
        for (int i = 0; i < 2; i++)
#pragma unroll
            for (int j = 0; j < 4; j++) acc[i][j] = (v4f)0.f;
#pragma unroll
        for (int ks = 0; ks < 2; ks++) {
            v8s b0 = *(const v8s*)(bb + ks * 32);
            v8s b1 = *(const v8s*)(bb + 16 * N_ + ks * 32);
            v8s b2 = *(const v8s*)(bb + 32 * N_ + ks * 32);
            v8s b3 = *(const v8s*)(bb + 48 * N_ + ks * 32);
            acc[0][0] = __builtin_amdgcn_mfma_f32_16x16x32_bf16(a[0][ks], b0, acc[0][0], 0, 0, 0);
            acc[0][1] = __builtin_amdgcn_mfma_f32_16x16x32_bf16(a[0][ks], b1, acc[0][1], 0, 0, 0);
            acc[0][2] = __builtin_amdgcn_mfma_f32_16x16x32_bf16(a[0][ks], b2, acc[0][2], 0, 0, 0);
            acc[0][3] = __builtin_amdgcn_mfma_f32_16x16x32_bf16(a[0][ks], b3, acc[0][3], 0, 0, 0);
            acc[1][0] = __builtin_amdgcn_mfma_f32_16x16x32_bf16(a[1][ks], b0, acc[1][0], 0, 0, 0);
            acc[1][1] = __builtin_amdgcn_mfma_f32_16x16x32_bf16(a[1][ks], b1, acc[1][1], 0, 0, 0);
            acc[1][2] = __builtin_amdgcn_mfma_f32_16x16x32_bf16(a[1][ks], b2, acc[1][2], 0, 0, 0);
            acc[1][3] = __builtin_amdgcn_mfma_f32_16x16x32_bf16(a[1][ks], b3, acc[1][3], 0, 0, 0);
        }
        __syncthreads();   // dt=0: all A-frag reads done (st death);
                           // dt>0: previous iteration's C-reads done
        // stash C in LDS (same proven layout)
#pragma unroll
        for (int i = 0; i < 2; i++)
#pragma unroll
            for (int j = 0; j < 4; j++)
#pragma unroll
                for (int r = 0; r < 4; r++)
                    C[(wm * 32 + i * 16 + quad * 4 + r) * 132 + wn * 64 + j * 16 + l15] = acc[i][j][r];
        __syncthreads();   // C fully written
        // coalesced stores: 8 lanes cover one row's 128B segment per instruction
#pragma unroll
        for (int rep = 0; rep < 2; rep++) {
            int row = rep * 32 + rrow;
            float* orow = out + ((size_t)(m0 + row)) * D_ + d0;
            const float* crow = &C[row * 132];
#pragma unroll
            for (int k = 0; k < 4; k++) {
                int col = ccol + k * 32;
                *(float4*)(orow + col) = *(const float4*)(crow + col);
            }
        }
    }
}

extern "C" void kernel_launch(void* const* d_in, const int* in_sizes, int n_in,
                              void* d_out, int out_size, void* d_ws, size_t ws_size,
                              hipStream_t stream) {
    const float* x    = (const float*)d_in[0];
    const float* tdec = (const float*)d_in[1];
    const float* tf   = (const float*)d_in[2];
    const float* keyw = (const float*)d_in[3];
    const float* valw = (const float*)d_in[4];
    const float* ow   = (const float*)d_in[5];
    const float* tsg  = (const float*)d_in[6];
    const float* lnw  = (const float*)d_in[7];
    const float* lnb  = (const float*)d_in[8];
    float* out = (float*)d_out;
    float* ws  = (float*)d_ws;

    // workspace layout (float offsets)
    float* g     = ws;                        // 1024
    float* etf   = g + 1024;                  // 64
    short* wbf   = (short*)(etf + 64);        // 131072 shorts = 65536 floats
    short* owbf  = (short*)(ws + 66624);      // 65536 shorts = 32768 floats
    float* mu    = ws + 99392;                // 32768
    float* rstd  = mu + 32768;                // 32768
    float* wkv   = rstd + 32768;              // 2097152
    float* Acar  = wkv + 2097152;             // 65536
    float* Cin   = Acar + 65536;              // 65536
    short* xnorm = (short*)(ws + 3441728);    // 33554432 shorts = 16777216 floats
    const size_t NEED_PRIMARY = (size_t)(3441728 + 16777216) * 4;  // ~80.9 MB

    k_conv<<<773, 256, 0, stream>>>(keyw, valw, ow, tf, tsg, wbf, owbf, etf, g);

    if (ws_size >= NEED_PRIMARY) {
        k_stats_fused<<<B_ * (S_ / 2), 256, 0, stream>>>(x, g, lnw, lnb, xnorm);
        // proj also emits Acar (chunk carries) -> no k_chunk in this path
        k_proj_mx<<<MTOT / 64, 256, 0, stream>>>(xnorm, wbf, etf, tdec, wkv, Acar);
    } else {
        k_stats_mu<<<B_ * (S_ / 2), 256, 0, stream>>>(x, g, mu, rstd);
        k_proj_fp32<<<MTOT / 64, 256, 0, stream>>>(x, keyw, valw, g, lnw, lnb, tf, mu, rstd, wkv);
        k_chunk <<<B_ * CCH, 64, 0, stream>>>(wkv, tdec, Acar);
    }
    k_carry <<<B_, 64, 0, stream>>>(Acar, tdec, Cin, out + (size_t)MTOT * D_);
    // rescan is fused into k_out_mx (reads wkv+Cin directly; no stbf buffer)
    k_out_mx<<<(MTOT / 64) * 2, 256, 0, stream>>>(wkv, Cin, tdec, owbf, out);
}

// Round 8
// 291.064 us; speedup vs baseline: 1.0494x; 1.0013x over previous
//
#include <hip/hip_runtime.h>
#include <math.h>

#define B_ 8
#define S_ 4096
#define D_ 1024
#define N_ 64
#define SHIFT_ 2048
#define LCH 32
#define CCH 128            // S_/LCH
#define MTOT (B_*S_)
#define EPS_ 1e-5f

typedef __attribute__((ext_vector_type(8))) short v8s;
typedef __attribute__((ext_vector_type(4))) float v4f;

static __device__ __forceinline__ short f2bf(float f) {
    // round-to-nearest-even fp32 -> bf16
    unsigned int u = __float_as_uint(f);
    u += 0x7fffu + ((u >> 16) & 1u);
    return (short)(u >> 16);
}

// async global->LDS, 16B per lane; LDS dest is wave-uniform base + lane*16
static __device__ __forceinline__ void gl_lds16(const void* g, void* l) {
    __builtin_amdgcn_global_load_lds(
        (const __attribute__((address_space(1))) unsigned int*)g,
        (__attribute__((address_space(3))) unsigned int*)l,
        16, 0, 0);
}

// ---------------- k_conv: weights->bf16, exp(tf), sigmoid(gates) ----------
__global__ __launch_bounds__(256) void k_conv(
    const float* __restrict__ keyw, const float* __restrict__ valw,
    const float* __restrict__ ow, const float* __restrict__ tf,
    const float* __restrict__ tsg,
    short* __restrict__ wbf, short* __restrict__ owbf,
    float* __restrict__ etf, float* __restrict__ g) {
    int i = blockIdx.x * 256 + threadIdx.x;
    if (i < 65536)          wbf[i] = f2bf(keyw[i]);
    else if (i < 131072)    wbf[i] = f2bf(valw[i - 65536]);
    else if (i < 196608)    owbf[i - 131072] = f2bf(ow[i - 131072]);
    else if (i < 196672)    etf[i - 196608] = __expf(tf[i - 196608]);
    else if (i < 197696) {
        int j = i - 196672;
        g[j] = 1.0f / (1.0f + __expf(-tsg[j]));
    }
}

// ---------------- PRIMARY: shift + full LN -> bf16 x_norm ------------------
// (round-2/7 replay-proven block-per-pair version)
__global__ __launch_bounds__(256) void k_stats_fused(
    const float* __restrict__ x, const float* __restrict__ g,
    const float* __restrict__ lnw, const float* __restrict__ lnb,
    short* __restrict__ xn) {
    int b = blockIdx.x >> 11;
    int t = blockIdx.x & 2047;
    const float* rowa = x + ((size_t)(b * S_ + t)) * D_;
    const float* rowb = rowa + (size_t)SHIFT_ * D_;
    int c = threadIdx.x * 4;
    float4 xa = *(const float4*)(rowa + c);
    float4 xb = *(const float4*)(rowb + c);
    float4 gg = *(const float4*)(g + c);
    float av[4] = {xa.x, xa.y, xa.z, xa.w};
    float bv[4] = {xb.x, xb.y, xb.z, xb.w};
    float gv[4] = {gg.x, gg.y, gg.z, gg.w};
    float u[4], w2[4];
    float s1 = 0.f, q1 = 0.f, s2 = 0.f, q2 = 0.f;
#pragma unroll
    for (int j = 0; j < 4; j++) {
        u[j]  = gv[j] * bv[j] + (1.f - gv[j]) * av[j];   // token t
        w2[j] = gv[j] * av[j] + (1.f - gv[j]) * bv[j];   // token t+2048
        s1 += u[j];  q1 += u[j] * u[j];
        s2 += w2[j]; q2 += w2[j] * w2[j];
    }
    __shared__ float red[4][4];
    int lane = threadIdx.x & 63, wv = threadIdx.x >> 6;
#pragma unroll
    for (int off = 32; off > 0; off >>= 1) {
        s1 += __shfl_down(s1, off);
        q1 += __shfl_down(q1, off);
        s2 += __shfl_down(s2, off);
        q2 += __shfl_down(q2, off);
    }
    if (lane == 0) { red[wv][0] = s1; red[wv][1] = q1; red[wv][2] = s2; red[wv][3] = q2; }
    __syncthreads();
    float S1 = red[0][0] + red[1][0] + red[2][0] + red[3][0];
    float Q1 = red[0][1] + red[1][1] + red[2][1] + red[3][1];
    float S2 = red[0][2] + red[1][2] + red[2][2] + red[3][2];
    float Q2 = red[0][3] + red[1][3] + red[2][3] + red[3][3];
    float m1 = S1 * (1.f / D_), m2 = S2 * (1.f / D_);
    float rs1 = rsqrtf(Q1 * (1.f / D_) - m1 * m1 + EPS_);
    float rs2 = rsqrtf(Q2 * (1.f / D_) - m2 * m2 + EPS_);
    float4 lw = *(const float4*)(lnw + c);
    float4 lb = *(const float4*)(lnb + c);
    float lwv[4] = {lw.x, lw.y, lw.z, lw.w};
    float lbv[4] = {lb.x, lb.y, lb.z, lb.w};
    short o1[4], o2[4];
#pragma unroll
    for (int j = 0; j < 4; j++) {
        o1[j] = f2bf((u[j]  - m1) * rs1 * lwv[j] + lbv[j]);
        o2[j] = f2bf((w2[j] - m2) * rs2 * lwv[j] + lbv[j]);
    }
    short* d1 = xn + ((size_t)(b * S_ + t)) * D_ + c;
    short* d2 = d1 + (size_t)SHIFT_ * D_;
    *(short4*)d1 = make_short4(o1[0], o1[1], o1[2], o1[3]);
    *(short4*)d2 = make_short4(o2[0], o2[1], o2[2], o2[3]);
}

// ---------------- PRIMARY: MFMA K/V projection (counted-vmcnt pipeline) -----
// C[64 tok][128 outs] = xnorm(64x1024) @ wbf^T
// T3+T4 upgrade of the proven m97 structure: TRIPLE-buffered LDS (72 KB,
// still 2 blocks/CU), stage 2 K-tiles ahead, and `s_waitcnt vmcnt(6)` +
// raw s_barrier instead of __syncthreads' vmcnt(0) drain. Each wave waits
// only for ITS OWN oldest stage (6 gl_lds calls in flight = newest stage);
// symmetric across waves + barrier => buf[cur] fully visible. Buffer-reuse
// safe: stage(kt+2) overwrites buf[(kt-1)%3], whose reads finished before
// the barrier all waves just passed. Last tile peeled with vmcnt(0).
// Epilogue (wkv + fused chunk scan) identical to the proven version.
__global__ __launch_bounds__(256) void k_proj_mx(
    const short* __restrict__ xn, const short* __restrict__ wbf,
    const float* __restrict__ etf, const float* __restrict__ tdec,
    float* __restrict__ wkv, float* __restrict__ Acar) {
    __shared__ __align__(16) char lds[73728];   // 3 x (8 KB A + 16 KB B)
    char* Ab = lds;                  // [3][8192] bytes
    char* Bb = lds + 24576;          // [3][16384] bytes
    float* C = (float*)lds;          // epilogue view, 64*132*4 = 33792 B

    int tid = threadIdx.x, wid = tid >> 6, lane = tid & 63;
    int wm = wid >> 1, wn = wid & 1;
    int quad = lane >> 4, l15 = lane & 15;
    int m0 = blockIdx.x * 64;

    const char* xb = (const char*)(xn + (size_t)m0 * D_);
    const char* wb = (const char*)wbf;

    v4f acc[2][4];
#pragma unroll
    for (int i = 0; i < 2; i++)
#pragma unroll
        for (int j = 0; j < 4; j++) acc[i][j] = (v4f)0.f;

    // 6 gl_lds per stage per wave (A:2, B:4) -> vmcnt unit = 6 per stage
    auto stage = [&](int buf, int k0) {
#pragma unroll
        for (int j = 0; j < 2; ++j) {
            int s = j * 256 + wid * 64 + lane;     // 16B slot 0..511
            int r = s >> 3, cu = s & 7;
            gl_lds16(xb + (size_t)r * 2048 + k0 * 2 + ((cu ^ (r & 7)) << 4),
                     Ab + buf * 8192 + (j * 256 + wid * 64) * 16);
        }
#pragma unroll
        for (int j = 0; j < 4; ++j) {
            int s = j * 256 + wid * 64 + lane;     // 16B slot 0..1023
            int r = s >> 3, cu = s & 7;
            gl_lds16(wb + (size_t)r * 2048 + k0 * 2 + ((cu ^ (r & 7)) << 4),
                     Bb + buf * 16384 + (j * 256 + wid * 64) * 16);
        }
    };
    auto ldA = [&](int buf, int r, int cu) -> v8s {
        return *(const v8s*)(Ab + buf * 8192 + r * 128 + ((cu ^ (r & 7)) << 4));
    };
    auto ldB = [&](int buf, int r, int cu) -> v8s {
        return *(const v8s*)(Bb + buf * 16384 + r * 128 + ((cu ^ (r & 7)) << 4));
    };
    auto compute = [&](int buf) {
#pragma unroll
        for (int kk2 = 0; kk2 < 2; ++kk2) {
            int cu = kk2 * 4 + quad;
            v8s a0 = ldA(buf, wm * 32 + l15, cu);
            v8s a1 = ldA(buf, wm * 32 + 16 + l15, cu);
            v8s b0 = ldB(buf, wn * 64 + l15, cu);
            v8s b1 = ldB(buf, wn * 64 + 16 + l15, cu);
            v8s b2 = ldB(buf, wn * 64 + 32 + l15, cu);
            v8s b3 = ldB(buf, wn * 64 + 48 + l15, cu);
            acc[0][0] = __builtin_amdgcn_mfma_f32_16x16x32_bf16(a0, b0, acc[0][0], 0, 0, 0);
            acc[0][1] = __builtin_amdgcn_mfma_f32_16x16x32_bf16(a0, b1, acc[0][1], 0, 0, 0);
            acc[0][2] = __builtin_amdgcn_mfma_f32_16x16x32_bf16(a0, b2, acc[0][2], 0, 0, 0);
            acc[0][3] = __builtin_amdgcn_mfma_f32_16x16x32_bf16(a0, b3, acc[0][3], 0, 0, 0);
            acc[1][0] = __builtin_amdgcn_mfma_f32_16x16x32_bf16(a1, b0, acc[1][0], 0, 0, 0);
            acc[1][1] = __builtin_amdgcn_mfma_f32_16x16x32_bf16(a1, b1, acc[1][1], 0, 0, 0);
            acc[1][2] = __builtin_amdgcn_mfma_f32_16x16x32_bf16(a1, b2, acc[1][2], 0, 0, 0);
            acc[1][3] = __builtin_amdgcn_mfma_f32_16x16x32_bf16(a1, b3, acc[1][3], 0, 0, 0);
        }
    };

    stage(0, 0);                     // K-tile 0
    stage(1, 64);                    // K-tile 1
    int cur = 0;
    for (int kt = 0; kt < 15; ++kt) {
        // wait for stage(kt) retired; allow stage(kt+1) (6 calls) in flight
        asm volatile("s_waitcnt vmcnt(6)" ::: "memory");
        __builtin_amdgcn_s_barrier();
        __builtin_amdgcn_sched_barrier(0);
        if (kt < 14) {
            int nb = cur + 2; if (nb >= 3) nb -= 3;
            stage(nb, (kt + 2) * 64);
        }
        compute(cur);
        cur = (cur == 2) ? 0 : cur + 1;
    }
    // last K-tile: full drain
    asm volatile("s_waitcnt vmcnt(0)" ::: "memory");
    __builtin_amdgcn_s_barrier();
    __builtin_amdgcn_sched_barrier(0);
    compute(cur);

    __syncthreads();   // all ds_reads done -> safe to overwrite LDS with C

    // C/D layout: col = lane&15, row = quad*4 + reg (proven mapping)
#pragma unroll
    for (int i = 0; i < 2; i++)
#pragma unroll
        for (int j = 0; j < 4; j++)
#pragma unroll
            for (int r = 0; r < 4; r++)
                C[(wm * 32 + i * 16 + quad * 4 + r) * 132 + wn * 64 + j * 16 + l15] = acc[i][j][r];
    __syncthreads();

    // wkv epilogue: tok = tid>>2 (0..63), 16 n's per thread
    int tok = tid >> 2, n0 = (tid & 3) * 16;
    float* orow = wkv + ((size_t)(m0 + tok)) * N_ + n0;
    float os[16];
#pragma unroll
    for (int jj = 0; jj < 16; jj++) {
        float kv = C[tok * 132 + n0 + jj];
        float vv = C[tok * 132 + 64 + n0 + jj];
        os[jj] = __expf(-etf[n0 + jj] * kv) * vv;
    }
#pragma unroll
    for (int jj = 0; jj < 16; jj += 4)
        *(float4*)(orow + jj) = make_float4(os[jj], os[jj + 1], os[jj + 2], os[jj + 3]);
    // stash wkv into k-region of C for the in-block chunk scan
    // (each thread overwrites only cells it alone read above -> no hazard)
#pragma unroll
    for (int jj = 0; jj < 16; jj++) C[tok * 132 + n0 + jj] = os[jj];
    __syncthreads();

    // chunk scan: 2 chunks of 32 tokens per block, 64 n's each -> 128 threads
    if (tid < 128) {
        int c = tid >> 6, n = tid & 63;
        float w = expf(tdec[n]);          // match k_carry/rescan precision
        float s = 0.f;
#pragma unroll
        for (int i = 0; i < LCH; i++) s = s * w + C[(c * 32 + i) * 132 + n];
        Acar[((size_t)blockIdx.x * 2 + c) * N_ + n] = s;
    }
}

// ---------------- FALLBACK: LN stats only ----------------------------------
__global__ __launch_bounds__(256) void k_stats_mu(const float* __restrict__ x,
                                                  const float* __restrict__ g,
                                                  float* __restrict__ mu,
                                                  float* __restrict__ rstd) {
    int b = blockIdx.x >> 11;
    int t = blockIdx.x & 2047;
    const float* rowa = x + ((size_t)(b * S_ + t)) * D_;
    const float* rowb = rowa + (size_t)SHIFT_ * D_;
    int c = threadIdx.x * 4;
    float4 xa = *(const float4*)(rowa + c);
    float4 xb = *(const float4*)(rowb + c);
    float4 gg = *(const float4*)(g + c);
    float av[4] = {xa.x, xa.y, xa.z, xa.w};
    float bv[4] = {xb.x, xb.y, xb.z, xb.w};
    float gv[4] = {gg.x, gg.y, gg.z, gg.w};
    float s1 = 0.f, q1 = 0.f, s2 = 0.f, q2 = 0.f;
#pragma unroll
    for (int j = 0; j < 4; j++) {
        float u  = gv[j] * bv[j] + (1.f - gv[j]) * av[j];
        float w2 = gv[j] * av[j] + (1.f - gv[j]) * bv[j];
        s1 += u;  q1 += u * u;
        s2 += w2; q2 += w2 * w2;
    }
    __shared__ float red[4][4];
    int lane = threadIdx.x & 63, wv = threadIdx.x >> 6;
#pragma unroll
    for (int off = 32; off > 0; off >>= 1) {
        s1 += __shfl_down(s1, off);
        q1 += __shfl_down(q1, off);
        s2 += __shfl_down(s2, off);
        q2 += __shfl_down(q2, off);
    }
    if (lane == 0) { red[wv][0] = s1; red[wv][1] = q1; red[wv][2] = s2; red[wv][3] = q2; }
    __syncthreads();
    if (threadIdx.x == 0) {
        float S1 = 0, Q1 = 0, S2 = 0, Q2 = 0;
#pragma unroll
        for (int i = 0; i < 4; i++) { S1 += red[i][0]; Q1 += red[i][1]; S2 += red[i][2]; Q2 += red[i][3]; }
        float m1 = S1 * (1.f / D_), m2 = S2 * (1.f / D_);
        float v1 = Q1 * (1.f / D_) - m1 * m1;
        float v2 = Q2 * (1.f / D_) - m2 * m2;
        int m = b * S_ + t;
        mu[m] = m1;           rstd[m] = rsqrtf(v1 + EPS_);
        mu[m + SHIFT_] = m2;  rstd[m + SHIFT_] = rsqrtf(v2 + EPS_);
    }
}

// ---------------- FALLBACK: fp32 fused projection (round-1, proven) --------
__global__ __launch_bounds__(256) void k_proj_fp32(
    const float* __restrict__ x, const float* __restrict__ keyw,
    const float* __restrict__ valw, const float* __restrict__ g,
    const float* __restrict__ lnw, const float* __restrict__ lnb,
    const float* __restrict__ tf, const float* __restrict__ mu,
    const float* __restrict__ rstd, float* __restrict__ wkv) {
    __shared__ float smem[64 * 132];
    float* As = smem;
    float* Bs = smem + 64 * 36;

    int m0 = blockIdx.x * 64;
    int b = m0 >> 12;
    int t0 = m0 & 4095;
    int t2 = (t0 + SHIFT_) & 4095;
    const float* xa_base = x + ((size_t)(b * S_ + t0)) * D_;
    const float* xb_base = x + ((size_t)(b * S_ + t2)) * D_;

    int tid = threadIdx.x;
    int ty = tid >> 4, tx = tid & 15;
    int tokA = tid >> 3;
    int cA = (tid & 7) * 4;

    float mu0 = mu[m0 + tokA],      rs0 = rstd[m0 + tokA];
    float mu1 = mu[m0 + tokA + 32], rs1 = rstd[m0 + tokA + 32];

    int nB = tid >> 1;
    int halfB = tid & 1;
    const float* wrow = (nB < 64) ? (keyw + (size_t)nB * D_)
                                  : (valw + (size_t)(nB - 64) * D_);

    float acc[4][8];
#pragma unroll
    for (int i = 0; i < 4; i++)
#pragma unroll
        for (int j = 0; j < 8; j++) acc[i][j] = 0.f;

    for (int kk0 = 0; kk0 < D_; kk0 += 32) {
        float4 gg = *(const float4*)(g + kk0 + cA);
        float4 lw = *(const float4*)(lnw + kk0 + cA);
        float4 lb = *(const float4*)(lnb + kk0 + cA);
        float gv[4] = {gg.x, gg.y, gg.z, gg.w};
        float lwv[4] = {lw.x, lw.y, lw.z, lw.w};
        float lbv[4] = {lb.x, lb.y, lb.z, lb.w};
#pragma unroll
        for (int r = 0; r < 2; r++) {
            int tok = tokA + r * 32;
            float4 xa = *(const float4*)(xa_base + (size_t)tok * D_ + kk0 + cA);
            float4 xb = *(const float4*)(xb_base + (size_t)tok * D_ + kk0 + cA);
            float xav[4] = {xa.x, xa.y, xa.z, xa.w};
            float xbv[4] = {xb.x, xb.y, xb.z, xb.w};
            float m_ = r ? mu1 : mu0;
            float rs_ = r ? rs1 : rs0;
#pragma unroll
            for (int j = 0; j < 4; j++) {
                float xs = gv[j] * xbv[j] + (1.f - gv[j]) * xav[j];
                As[tok * 36 + cA + j] = (xs - m_) * rs_ * lwv[j] + lbv[j];
            }
        }
#pragma unroll
        for (int cc = 0; cc < 16; cc += 4) {
            int kk = halfB * 16 + cc;
            float4 wv4 = *(const float4*)(wrow + kk0 + kk);
            Bs[(kk + 0) * 132 + nB] = wv4.x;
            Bs[(kk + 1) * 132 + nB] = wv4.y;
            Bs[(kk + 2) * 132 + nB] = wv4.z;
            Bs[(kk + 3) * 132 + nB] = wv4.w;
        }
        __syncthreads();
#pragma unroll
        for (int kk = 0; kk < 32; kk++) {
            float a0 = As[(ty * 4 + 0) * 36 + kk];
            float a1 = As[(ty * 4 + 1) * 36 + kk];
            float a2 = As[(ty * 4 + 2) * 36 + kk];
            float a3 = As[(ty * 4 + 3) * 36 + kk];
            float bvv[8];
#pragma unroll
            for (int j = 0; j < 8; j++) bvv[j] = Bs[kk * 132 + tx * 8 + j];
#pragma unroll
            for (int j = 0; j < 8; j++) {
                acc[0][j] = fmaf(a0, bvv[j], acc[0][j]);
                acc[1][j] = fmaf(a1, bvv[j], acc[1][j]);
                acc[2][j] = fmaf(a2, bvv[j], acc[2][j]);
                acc[3][j] = fmaf(a3, bvv[j], acc[3][j]);
            }
        }
        __syncthreads();
    }
#pragma unroll
    for (int i = 0; i < 4; i++)
#pragma unroll
        for (int j = 0; j < 8; j++)
            smem[(ty * 4 + i) * 132 + tx * 8 + j] = acc[i][j];
    __syncthreads();
    {
        int tok = tid >> 2;
        int n0 = (tid & 3) * 16;
        float* orow = wkv + ((size_t)(m0 + tok)) * N_ + n0;
#pragma unroll
        for (int jj = 0; jj < 16; jj++) {
            int n = n0 + jj;
            float kv = smem[tok * 132 + n];
            float vv = smem[tok * 132 + 64 + n];
            orow[jj] = __expf(-__expf(tf[n]) * kv) * vv;
        }
    }
}

// ---------------- scan: per-chunk local -> carries (FALLBACK path only) -----
__global__ __launch_bounds__(64) void k_chunk(const float* __restrict__ wkv,
                                              const float* __restrict__ tdec,
                                              float* __restrict__ Acar) {
    int idx = blockIdx.x;
    int n = threadIdx.x;
    float w = expf(tdec[n]);
    const float* p = wkv + (size_t)idx * (LCH * N_) + n;
    float s = 0.f;
#pragma unroll
    for (int i = 0; i < LCH; i++) s = s * w + p[i * N_];
    Acar[idx * N_ + n] = s;
}

// ---------------- scan: carries across chunks; write last_states -----------
__global__ __launch_bounds__(64) void k_carry(const float* __restrict__ Acar,
                                              const float* __restrict__ tdec,
                                              float* __restrict__ Cin,
                                              float* __restrict__ last) {
    int b = blockIdx.x;
    int n = threadIdx.x;
    float wL = expf(tdec[n] * (float)LCH);
    float c = 0.f;
#pragma unroll 16
    for (int ch = 0; ch < CCH; ch++) {
        Cin[(b * CCH + ch) * N_ + n] = c;
        c = c * wL + Acar[(b * CCH + ch) * N_ + n];
    }
    last[b * N_ + n] = c;
}

// ---------------- output projection, rescan FUSED in ------------------------
// (byte-identical to round-7 replay-proven version)
__global__ __launch_bounds__(256) void k_out_mx(const float* __restrict__ wkv,
                                                const float* __restrict__ Cin,
                                                const float* __restrict__ tdec,
                                                const short* __restrict__ owbf,
                                                float* __restrict__ out) {
    __shared__ __align__(16) char smem[64 * 132 * 4];   // 33.8 KB
    char* stl = smem;               // phase-1 view: [64 rows][128 B] swizzled bf16
    float* C = (float*)smem;        // phase-2 view

    int tid = threadIdx.x, wid = tid >> 6, lane = tid & 63;
    int wm = wid >> 1, wn = wid & 1;
    int quad = lane >> 4, l15 = lane & 15;
    int m0 = (blockIdx.x >> 1) * 64;
    int dh = blockIdx.x & 1;        // d-half: 0 -> d 0..511, 1 -> 512..1023

    // ---- phase 1: rescan 2 chunks into swizzled LDS bf16 tile ----
    if (tid < 128) {
        int c = tid >> 6, n = tid & 63;
        int idx = (blockIdx.x >> 1) * 2 + c;           // global chunk index
        float w = expf(tdec[n]);                       // matches k_carry/k_chunk
        float s = Cin[idx * N_ + n];
        const float* p = wkv + (size_t)idx * (LCH * N_) + n;
        int cu = (n * 2) >> 4, off = (n * 2) & 15;     // 16B unit + byte within
#pragma unroll
        for (int i = 0; i < LCH; i++) {
            s = s * w + p[i * N_];
            int row = c * 32 + i;
            *(short*)(stl + row * 128 + ((cu ^ (row & 7)) << 4) + off) = f2bf(s);
        }
    }
    __syncthreads();   // st tile ready

    // ---- A fragments once into registers (swizzled LDS read) ----
    v8s a[2][2];
#pragma unroll
    for (int i = 0; i < 2; i++)
#pragma unroll
        for (int ks = 0; ks < 2; ks++) {
            int row = wm * 32 + i * 16 + l15;
            int cu = quad + ks * 4;                    // col = quad*8 + ks*32 bf16
            a[i][ks] = *(const v8s*)(stl + row * 128 + ((cu ^ (row & 7)) << 4));
        }

    int rrow = tid >> 3;
    int ccol = (tid & 7) * 4;

    for (int dt = 0; dt < 4; ++dt) {
        int d0 = (dh * 4 + dt) * 128;
        const short* bb = owbf + ((size_t)(d0 + wn * 64 + l15)) * N_ + quad * 8;
        v4f acc[2][4];
#pragma unroll
        for (int i = 0; i < 2; i++)
#pragma unroll
            for (int j = 0; j < 4; j++) acc[i][j] = (v4f)0.f;
#pragma unroll
        for (int ks = 0; ks < 2; ks++) {
            v8s b0 = *(const v8s*)(bb + ks * 32);
            v8s b1 = *(const v8s*)(bb + 16 * N_ + ks * 32);
            v8s b2 = *(const v8s*)(bb + 32 * N_ + ks * 32);
            v8s b3 = *(const v8s*)(bb + 48 * N_ + ks * 32);
            acc[0][0] = __builtin_amdgcn_mfma_f32_16x16x32_bf16(a[0][ks], b0, acc[0][0], 0, 0, 0);
            acc[0][1] = __builtin_amdgcn_mfma_f32_16x16x32_bf16(a[0][ks], b1, acc[0][1], 0, 0, 0);
            acc[0][2] = __builtin_amdgcn_mfma_f32_16x16x32_bf16(a[0][ks], b2, acc[0][2], 0, 0, 0);
            acc[0][3] = __builtin_amdgcn_mfma_f32_16x16x32_bf16(a[0][ks], b3, acc[0][3], 0, 0, 0);
            acc[1][0] = __builtin_amdgcn_mfma_f32_16x16x32_bf16(a[1][ks], b0, acc[1][0], 0, 0, 0);
            acc[1][1] = __builtin_amdgcn_mfma_f32_16x16x32_bf16(a[1][ks], b1, acc[1][1], 0, 0, 0);
            acc[1][2] = __builtin_amdgcn_mfma_f32_16x16x32_bf16(a[1][ks], b2, acc[1][2], 0, 0, 0);
            acc[1][3] = __builtin_amdgcn_mfma_f32_16x16x32_bf16(a[1][ks], b3, acc[1][3], 0, 0, 0);
        }
        __syncthreads();   // dt=0: all A-frag reads done (st death);
                           // dt>0: previous iteration's C-reads done
        // stash C in LDS (same proven layout)
#pragma unroll
        for (int i = 0; i < 2; i++)
#pragma unroll
            for (int j = 0; j < 4; j++)
#pragma unroll
                for (int r = 0; r < 4; r++)
                    C[(wm * 32 + i * 16 + quad * 4 + r) * 132 + wn * 64 + j * 16 + l15] = acc[i][j][r];
        __syncthreads();   // C fully written
        // coalesced stores: 8 lanes cover one row's 128B segment per instruction
#pragma unroll
        for (int rep = 0; rep < 2; rep++) {
            int row = rep * 32 + rrow;
            float* orow = out + ((size_t)(m0 + row)) * D_ + d0;
            const float* crow = &C[row * 132];
#pragma unroll
            for (int k = 0; k < 4; k++) {
                int col = ccol + k * 32;
                *(float4*)(orow + col) = *(const float4*)(crow + col);
            }
        }
    }
}

extern "C" void kernel_launch(void* const* d_in, const int* in_sizes, int n_in,
                              void* d_out, int out_size, void* d_ws, size_t ws_size,
                              hipStream_t stream) {
    const float* x    = (const float*)d_in[0];
    const float* tdec = (const float*)d_in[1];
    const float* tf   = (const float*)d_in[2];
    const float* keyw = (const float*)d_in[3];
    const float* valw = (const float*)d_in[4];
    const float* ow   = (const float*)d_in[5];
    const float* tsg  = (const float*)d_in[6];
    const float* lnw  = (const float*)d_in[7];
    const float* lnb  = (const float*)d_in[8];
    float* out = (float*)d_out;
    float* ws  = (float*)d_ws;

    // workspace layout (float offsets)
    float* g     = ws;                        // 1024
    float* etf   = g + 1024;                  // 64
    short* wbf   = (short*)(etf + 64);        // 131072 shorts = 65536 floats
    short* owbf  = (short*)(ws + 66624);      // 65536 shorts = 32768 floats
    float* mu    = ws + 99392;                // 32768
    float* rstd  = mu + 32768;                // 32768
    float* wkv   = rstd + 32768;              // 2097152
    float* Acar  = wkv + 2097152;             // 65536
    float* Cin   = Acar + 65536;              // 65536
    short* xnorm = (short*)(ws + 3441728);    // 33554432 shorts = 16777216 floats
    const size_t NEED_PRIMARY = (size_t)(3441728 + 16777216) * 4;  // ~80.9 MB

    k_conv<<<773, 256, 0, stream>>>(keyw, valw, ow, tf, tsg, wbf, owbf, etf, g);

    if (ws_size >= NEED_PRIMARY) {
        k_stats_fused<<<B_ * (S_ / 2), 256, 0, stream>>>(x, g, lnw, lnb, xnorm);
        // proj also emits Acar (chunk carries) -> no k_chunk in this path
        k_proj_mx<<<MTOT / 64, 256, 0, stream>>>(xnorm, wbf, etf, tdec, wkv, Acar);
    } else {
        k_stats_mu<<<B_ * (S_ / 2), 256, 0, stream>>>(x, g, mu, rstd);
        k_proj_fp32<<<MTOT / 64, 256, 0, stream>>>(x, keyw, valw, g, lnw, lnb, tf, mu, rstd, wkv);
        k_chunk <<<B_ * CCH, 64, 0, stream>>>(wkv, tdec, Acar);
    }
    k_carry <<<B_, 64, 0, stream>>>(Acar, tdec, Cin, out + (size_t)MTOT * D_);
    // rescan is fused into k_out_mx (reads wkv+Cin directly; no stbf buffer)
    k_out_mx<<<(MTOT / 64) * 2, 256, 0, stream>>>(wkv, Cin, tdec, owbf, out);
}

// Round 9
// 286.334 us; speedup vs baseline: 1.0667x; 1.0165x over previous
//
#include <hip/hip_runtime.h>
#include <math.h>

#define B_ 8
#define S_ 4096
#define D_ 1024
#define N_ 64
#define SHIFT_ 2048
#define LCH 32
#define CCH 128            // S_/LCH
#define MTOT (B_*S_)
#define EPS_ 1e-5f

typedef __attribute__((ext_vector_type(8))) short v8s;
typedef __attribute__((ext_vector_type(4))) float v4f;

static __device__ __forceinline__ short f2bf(float f) {
    // round-to-nearest-even fp32 -> bf16
    unsigned int u = __float_as_uint(f);
    u += 0x7fffu + ((u >> 16) & 1u);
    return (short)(u >> 16);
}
static __device__ __forceinline__ float bf2f(short s) {
    return __uint_as_float(((unsigned int)(unsigned short)s) << 16);
}

// async global->LDS, 16B per lane; LDS dest is wave-uniform base + lane*16
static __device__ __forceinline__ void gl_lds16(const void* g, void* l) {
    __builtin_amdgcn_global_load_lds(
        (const __attribute__((address_space(1))) unsigned int*)g,
        (__attribute__((address_space(3))) unsigned int*)l,
        16, 0, 0);
}

// ---------------- k_conv: weights->bf16, exp(tf), sigmoid(gates) ----------
// (FALLBACK path only; primary path does this inside k_stats_conv)
__global__ __launch_bounds__(256) void k_conv(
    const float* __restrict__ keyw, const float* __restrict__ valw,
    const float* __restrict__ ow, const float* __restrict__ tf,
    const float* __restrict__ tsg,
    short* __restrict__ wbf, short* __restrict__ owbf,
    float* __restrict__ etf, float* __restrict__ g) {
    int i = blockIdx.x * 256 + threadIdx.x;
    if (i < 65536)          wbf[i] = f2bf(keyw[i]);
    else if (i < 131072)    wbf[i] = f2bf(valw[i - 65536]);
    else if (i < 196608)    owbf[i - 131072] = f2bf(ow[i - 131072]);
    else if (i < 196672)    etf[i - 196608] = __expf(tf[i - 196608]);
    else if (i < 197696) {
        int j = i - 196672;
        g[j] = 1.0f / (1.0f + __expf(-tsg[j]));
    }
}

// ---------------- PRIMARY: shift + full LN -> bf16 x_norm, conv merged -----
// Blocks [0,16384): round-2/7 replay-proven block-per-pair stats, with the
// token-shift gate computed inline as sigmoid(tsg) (breaks the conv->stats
// dependency). Blocks [16384,16384+773): the conv work (weights->bf16 etc),
// overlapped under the stats kernel's BW instead of a separate launch.
__global__ __launch_bounds__(256) void k_stats_conv(
    const float* __restrict__ x, const float* __restrict__ tsg,
    const float* __restrict__ lnw, const float* __restrict__ lnb,
    short* __restrict__ xn,
    const float* __restrict__ keyw, const float* __restrict__ valw,
    const float* __restrict__ ow, const float* __restrict__ tf,
    short* __restrict__ wbf, short* __restrict__ owbf,
    float* __restrict__ etf, float* __restrict__ g) {
    if (blockIdx.x >= 16384) {               // ---- conv tail blocks ----
        int i = (blockIdx.x - 16384) * 256 + threadIdx.x;
        if (i < 65536)          wbf[i] = f2bf(keyw[i]);
        else if (i < 131072)    wbf[i] = f2bf(valw[i - 65536]);
        else if (i < 196608)    owbf[i - 131072] = f2bf(ow[i - 131072]);
        else if (i < 196672)    etf[i - 196608] = __expf(tf[i - 196608]);
        else if (i < 197696) {
            int j = i - 196672;
            g[j] = 1.0f / (1.0f + __expf(-tsg[j]));
        }
        return;
    }
    int b = blockIdx.x >> 11;
    int t = blockIdx.x & 2047;
    const float* rowa = x + ((size_t)(b * S_ + t)) * D_;
    const float* rowb = rowa + (size_t)SHIFT_ * D_;
    int c = threadIdx.x * 4;
    float4 xa = *(const float4*)(rowa + c);
    float4 xb = *(const float4*)(rowb + c);
    float4 tg = *(const float4*)(tsg + c);
    float av[4] = {xa.x, xa.y, xa.z, xa.w};
    float bv[4] = {xb.x, xb.y, xb.z, xb.w};
    float gv[4] = {1.0f / (1.0f + __expf(-tg.x)), 1.0f / (1.0f + __expf(-tg.y)),
                   1.0f / (1.0f + __expf(-tg.z)), 1.0f / (1.0f + __expf(-tg.w))};
    float u[4], w2[4];
    float s1 = 0.f, q1 = 0.f, s2 = 0.f, q2 = 0.f;
#pragma unroll
    for (int j = 0; j < 4; j++) {
        u[j]  = gv[j] * bv[j] + (1.f - gv[j]) * av[j];   // token t
        w2[j] = gv[j] * av[j] + (1.f - gv[j]) * bv[j];   // token t+2048
        s1 += u[j];  q1 += u[j] * u[j];
        s2 += w2[j]; q2 += w2[j] * w2[j];
    }
    __shared__ float red[4][4];
    int lane = threadIdx.x & 63, wv = threadIdx.x >> 6;
#pragma unroll
    for (int off = 32; off > 0; off >>= 1) {
        s1 += __shfl_down(s1, off);
        q1 += __shfl_down(q1, off);
        s2 += __shfl_down(s2, off);
        q2 += __shfl_down(q2, off);
    }
    if (lane == 0) { red[wv][0] = s1; red[wv][1] = q1; red[wv][2] = s2; red[wv][3] = q2; }
    __syncthreads();
    float S1 = red[0][0] + red[1][0] + red[2][0] + red[3][0];
    float Q1 = red[0][1] + red[1][1] + red[2][1] + red[3][1];
    float S2 = red[0][2] + red[1][2] + red[2][2] + red[3][2];
    float Q2 = red[0][3] + red[1][3] + red[2][3] + red[3][3];
    float m1 = S1 * (1.f / D_), m2 = S2 * (1.f / D_);
    float rs1 = rsqrtf(Q1 * (1.f / D_) - m1 * m1 + EPS_);
    float rs2 = rsqrtf(Q2 * (1.f / D_) - m2 * m2 + EPS_);
    float4 lw = *(const float4*)(lnw + c);
    float4 lb = *(const float4*)(lnb + c);
    float lwv[4] = {lw.x, lw.y, lw.z, lw.w};
    float lbv[4] = {lb.x, lb.y, lb.z, lb.w};
    short o1[4], o2[4];
#pragma unroll
    for (int j = 0; j < 4; j++) {
        o1[j] = f2bf((u[j]  - m1) * rs1 * lwv[j] + lbv[j]);
        o2[j] = f2bf((w2[j] - m2) * rs2 * lwv[j] + lbv[j]);
    }
    short* d1 = xn + ((size_t)(b * S_ + t)) * D_ + c;
    short* d2 = d1 + (size_t)SHIFT_ * D_;
    *(short4*)d1 = make_short4(o1[0], o1[1], o1[2], o1[3]);
    *(short4*)d2 = make_short4(o2[0], o2[1], o2[2], o2[3]);
}

// ---------------- PRIMARY: MFMA K/V projection (counted-vmcnt pipeline) -----
// (replay-proven round-8 structure; epilogue now writes wkv as BF16 —
//  Acar chunk-scan still computed from the f32 values in LDS, unchanged)
__global__ __launch_bounds__(256) void k_proj_mx(
    const short* __restrict__ xn, const short* __restrict__ wbf,
    const float* __restrict__ etf, const float* __restrict__ tdec,
    short* __restrict__ wkvb, float* __restrict__ Acar) {
    __shared__ __align__(16) char lds[73728];   // 3 x (8 KB A + 16 KB B)
    char* Ab = lds;                  // [3][8192] bytes
    char* Bb = lds + 24576;          // [3][16384] bytes
    float* C = (float*)lds;          // epilogue view, 64*132*4 = 33792 B

    int tid = threadIdx.x, wid = tid >> 6, lane = tid & 63;
    int wm = wid >> 1, wn = wid & 1;
    int quad = lane >> 4, l15 = lane & 15;
    int m0 = blockIdx.x * 64;

    const char* xb = (const char*)(xn + (size_t)m0 * D_);
    const char* wb = (const char*)wbf;

    v4f acc[2][4];
#pragma unroll
    for (int i = 0; i < 2; i++)
#pragma unroll
        for (int j = 0; j < 4; j++) acc[i][j] = (v4f)0.f;

    // 6 gl_lds per stage per wave (A:2, B:4) -> vmcnt unit = 6 per stage
    auto stage = [&](int buf, int k0) {
#pragma unroll
        for (int j = 0; j < 2; ++j) {
            int s = j * 256 + wid * 64 + lane;     // 16B slot 0..511
            int r = s >> 3, cu = s & 7;
            gl_lds16(xb + (size_t)r * 2048 + k0 * 2 + ((cu ^ (r & 7)) << 4),
                     Ab + buf * 8192 + (j * 256 + wid * 64) * 16);
        }
#pragma unroll
        for (int j = 0; j < 4; ++j) {
            int s = j * 256 + wid * 64 + lane;     // 16B slot 0..1023
            int r = s >> 3, cu = s & 7;
            gl_lds16(wb + (size_t)r * 2048 + k0 * 2 + ((cu ^ (r & 7)) << 4),
                     Bb + buf * 16384 + (j * 256 + wid * 64) * 16);
        }
    };
    auto ldA = [&](int buf, int r, int cu) -> v8s {
        return *(const v8s*)(Ab + buf * 8192 + r * 128 + ((cu ^ (r & 7)) << 4));
    };
    auto ldB = [&](int buf, int r, int cu) -> v8s {
        return *(const v8s*)(Bb + buf * 16384 + r * 128 + ((cu ^ (r & 7)) << 4));
    };
    auto compute = [&](int buf) {
#pragma unroll
        for (int kk2 = 0; kk2 < 2; ++kk2) {
            int cu = kk2 * 4 + quad;
            v8s a0 = ldA(buf, wm * 32 + l15, cu);
            v8s a1 = ldA(buf, wm * 32 + 16 + l15, cu);
            v8s b0 = ldB(buf, wn * 64 + l15, cu);
            v8s b1 = ldB(buf, wn * 64 + 16 + l15, cu);
            v8s b2 = ldB(buf, wn * 64 + 32 + l15, cu);
            v8s b3 = ldB(buf, wn * 64 + 48 + l15, cu);
            acc[0][0] = __builtin_amdgcn_mfma_f32_16x16x32_bf16(a0, b0, acc[0][0], 0, 0, 0);
            acc[0][1] = __builtin_amdgcn_mfma_f32_16x16x32_bf16(a0, b1, acc[0][1], 0, 0, 0);
            acc[0][2] = __builtin_amdgcn_mfma_f32_16x16x32_bf16(a0, b2, acc[0][2], 0, 0, 0);
            acc[0][3] = __builtin_amdgcn_mfma_f32_16x16x32_bf16(a0, b3, acc[0][3], 0, 0, 0);
            acc[1][0] = __builtin_amdgcn_mfma_f32_16x16x32_bf16(a1, b0, acc[1][0], 0, 0, 0);
            acc[1][1] = __builtin_amdgcn_mfma_f32_16x16x32_bf16(a1, b1, acc[1][1], 0, 0, 0);
            acc[1][2] = __builtin_amdgcn_mfma_f32_16x16x32_bf16(a1, b2, acc[1][2], 0, 0, 0);
            acc[1][3] = __builtin_amdgcn_mfma_f32_16x16x32_bf16(a1, b3, acc[1][3], 0, 0, 0);
        }
    };

    stage(0, 0);                     // K-tile 0
    stage(1, 64);                    // K-tile 1
    int cur = 0;
    for (int kt = 0; kt < 15; ++kt) {
        asm volatile("s_waitcnt vmcnt(6)" ::: "memory");
        __builtin_amdgcn_s_barrier();
        __builtin_amdgcn_sched_barrier(0);
        if (kt < 14) {
            int nb = cur + 2; if (nb >= 3) nb -= 3;
            stage(nb, (kt + 2) * 64);
        }
        compute(cur);
        cur = (cur == 2) ? 0 : cur + 1;
    }
    asm volatile("s_waitcnt vmcnt(0)" ::: "memory");
    __builtin_amdgcn_s_barrier();
    __builtin_amdgcn_sched_barrier(0);
    compute(cur);

    __syncthreads();   // all ds_reads done -> safe to overwrite LDS with C

    // C/D layout: col = lane&15, row = quad*4 + reg (proven mapping)
#pragma unroll
    for (int i = 0; i < 2; i++)
#pragma unroll
        for (int j = 0; j < 4; j++)
#pragma unroll
            for (int r = 0; r < 4; r++)
                C[(wm * 32 + i * 16 + quad * 4 + r) * 132 + wn * 64 + j * 16 + l15] = acc[i][j][r];
    __syncthreads();

    // wkv epilogue: tok = tid>>2 (0..63), 16 n's per thread -> bf16 stores
    int tok = tid >> 2, n0 = (tid & 3) * 16;
    short* orow = wkvb + ((size_t)(m0 + tok)) * N_ + n0;
    float os[16];
#pragma unroll
    for (int jj = 0; jj < 16; jj++) {
        float kv = C[tok * 132 + n0 + jj];
        float vv = C[tok * 132 + 64 + n0 + jj];
        os[jj] = __expf(-etf[n0 + jj] * kv) * vv;
    }
    v8s w0, w1;
#pragma unroll
    for (int jj = 0; jj < 8; jj++) { w0[jj] = f2bf(os[jj]); w1[jj] = f2bf(os[8 + jj]); }
    *(v8s*)orow = w0;
    *(v8s*)(orow + 8) = w1;
    // stash f32 wkv into k-region of C for the in-block chunk scan (exact)
#pragma unroll
    for (int jj = 0; jj < 16; jj++) C[tok * 132 + n0 + jj] = os[jj];
    __syncthreads();

    // chunk scan: 2 chunks of 32 tokens per block, 64 n's each -> 128 threads
    if (tid < 128) {
        int c = tid >> 6, n = tid & 63;
        float w = expf(tdec[n]);          // match k_carry/rescan precision
        float s = 0.f;
#pragma unroll
        for (int i = 0; i < LCH; i++) s = s * w + C[(c * 32 + i) * 132 + n];
        Acar[((size_t)blockIdx.x * 2 + c) * N_ + n] = s;
    }
}

// ---------------- FALLBACK: LN stats only ----------------------------------
__global__ __launch_bounds__(256) void k_stats_mu(const float* __restrict__ x,
                                                  const float* __restrict__ g,
                                                  float* __restrict__ mu,
                                                  float* __restrict__ rstd) {
    int b = blockIdx.x >> 11;
    int t = blockIdx.x & 2047;
    const float* rowa = x + ((size_t)(b * S_ + t)) * D_;
    const float* rowb = rowa + (size_t)SHIFT_ * D_;
    int c = threadIdx.x * 4;
    float4 xa = *(const float4*)(rowa + c);
    float4 xb = *(const float4*)(rowb + c);
    float4 gg = *(const float4*)(g + c);
    float av[4] = {xa.x, xa.y, xa.z, xa.w};
    float bv[4] = {xb.x, xb.y, xb.z, xb.w};
    float gv[4] = {gg.x, gg.y, gg.z, gg.w};
    float s1 = 0.f, q1 = 0.f, s2 = 0.f, q2 = 0.f;
#pragma unroll
    for (int j = 0; j < 4; j++) {
        float u  = gv[j] * bv[j] + (1.f - gv[j]) * av[j];
        float w2 = gv[j] * av[j] + (1.f - gv[j]) * bv[j];
        s1 += u;  q1 += u * u;
        s2 += w2; q2 += w2 * w2;
    }
    __shared__ float red[4][4];
    int lane = threadIdx.x & 63, wv = threadIdx.x >> 6;
#pragma unroll
    for (int off = 32; off > 0; off >>= 1) {
        s1 += __shfl_down(s1, off);
        q1 += __shfl_down(q1, off);
        s2 += __shfl_down(s2, off);
        q2 += __shfl_down(q2, off);
    }
    if (lane == 0) { red[wv][0] = s1; red[wv][1] = q1; red[wv][2] = s2; red[wv][3] = q2; }
    __syncthreads();
    if (threadIdx.x == 0) {
        float S1 = 0, Q1 = 0, S2 = 0, Q2 = 0;
#pragma unroll
        for (int i = 0; i < 4; i++) { S1 += red[i][0]; Q1 += red[i][1]; S2 += red[i][2]; Q2 += red[i][3]; }
        float m1 = S1 * (1.f / D_), m2 = S2 * (1.f / D_);
        float v1 = Q1 * (1.f / D_) - m1 * m1;
        float v2 = Q2 * (1.f / D_) - m2 * m2;
        int m = b * S_ + t;
        mu[m] = m1;           rstd[m] = rsqrtf(v1 + EPS_);
        mu[m + SHIFT_] = m2;  rstd[m + SHIFT_] = rsqrtf(v2 + EPS_);
    }
}

// ---------------- FALLBACK: fp32 fused projection (bf16 wkv out) -----------
__global__ __launch_bounds__(256) void k_proj_fp32(
    const float* __restrict__ x, const float* __restrict__ keyw,
    const float* __restrict__ valw, const float* __restrict__ g,
    const float* __restrict__ lnw, const float* __restrict__ lnb,
    const float* __restrict__ tf, const float* __restrict__ mu,
    const float* __restrict__ rstd, short* __restrict__ wkvb) {
    __shared__ float smem[64 * 132];
    float* As = smem;
    float* Bs = smem + 64 * 36;

    int m0 = blockIdx.x * 64;
    int b = m0 >> 12;
    int t0 = m0 & 4095;
    int t2 = (t0 + SHIFT_) & 4095;
    const float* xa_base = x + ((size_t)(b * S_ + t0)) * D_;
    const float* xb_base = x + ((size_t)(b * S_ + t2)) * D_;

    int tid = threadIdx.x;
    int ty = tid >> 4, tx = tid & 15;
    int tokA = tid >> 3;
    int cA = (tid & 7) * 4;

    float mu0 = mu[m0 + tokA],      rs0 = rstd[m0 + tokA];
    float mu1 = mu[m0 + tokA + 32], rs1 = rstd[m0 + tokA + 32];

    int nB = tid >> 1;
    int halfB = tid & 1;
    const float* wrow = (nB < 64) ? (keyw + (size_t)nB * D_)
                                  : (valw + (size_t)(nB - 64) * D_);

    float acc[4][8];
#pragma unroll
    for (int i = 0; i < 4; i++)
#pragma unroll
        for (int j = 0; j < 8; j++) acc[i][j] = 0.f;

    for (int kk0 = 0; kk0 < D_; kk0 += 32) {
        float4 gg = *(const float4*)(g + kk0 + cA);
        float4 lw = *(const float4*)(lnw + kk0 + cA);
        float4 lb = *(const float4*)(lnb + kk0 + cA);
        float gv[4] = {gg.x, gg.y, gg.z, gg.w};
        float lwv[4] = {lw.x, lw.y, lw.z, lw.w};
        float lbv[4] = {lb.x, lb.y, lb.z, lb.w};
#pragma unroll
        for (int r = 0; r < 2; r++) {
            int tok = tokA + r * 32;
            float4 xa = *(const float4*)(xa_base + (size_t)tok * D_ + kk0 + cA);
            float4 xb = *(const float4*)(xb_base + (size_t)tok * D_ + kk0 + cA);
            float xav[4] = {xa.x, xa.y, xa.z, xa.w};
            float xbv[4] = {xb.x, xb.y, xb.z, xb.w};
            float m_ = r ? mu1 : mu0;
            float rs_ = r ? rs1 : rs0;
#pragma unroll
            for (int j = 0; j < 4; j++) {
                float xs = gv[j] * xbv[j] + (1.f - gv[j]) * xav[j];
                As[tok * 36 + cA + j] = (xs - m_) * rs_ * lwv[j] + lbv[j];
            }
        }
#pragma unroll
        for (int cc = 0; cc < 16; cc += 4) {
            int kk = halfB * 16 + cc;
            float4 wv4 = *(const float4*)(wrow + kk0 + kk);
            Bs[(kk + 0) * 132 + nB] = wv4.x;
            Bs[(kk + 1) * 132 + nB] = wv4.y;
            Bs[(kk + 2) * 132 + nB] = wv4.z;
            Bs[(kk + 3) * 132 + nB] = wv4.w;
        }
        __syncthreads();
#pragma unroll
        for (int kk = 0; kk < 32; kk++) {
            float a0 = As[(ty * 4 + 0) * 36 + kk];
            float a1 = As[(ty * 4 + 1) * 36 + kk];
            float a2 = As[(ty * 4 + 2) * 36 + kk];
            float a3 = As[(ty * 4 + 3) * 36 + kk];
            float bvv[8];
#pragma unroll
            for (int j = 0; j < 8; j++) bvv[j] = Bs[kk * 132 + tx * 8 + j];
#pragma unroll
            for (int j = 0; j < 8; j++) {
                acc[0][j] = fmaf(a0, bvv[j], acc[0][j]);
                acc[1][j] = fmaf(a1, bvv[j], acc[1][j]);
                acc[2][j] = fmaf(a2, bvv[j], acc[2][j]);
                acc[3][j] = fmaf(a3, bvv[j], acc[3][j]);
            }
        }
        __syncthreads();
    }
#pragma unroll
    for (int i = 0; i < 4; i++)
#pragma unroll
        for (int j = 0; j < 8; j++)
            smem[(ty * 4 + i) * 132 + tx * 8 + j] = acc[i][j];
    __syncthreads();
    {
        int tok = tid >> 2;
        int n0 = (tid & 3) * 16;
        short* orow = wkvb + ((size_t)(m0 + tok)) * N_ + n0;
#pragma unroll
        for (int jj = 0; jj < 16; jj++) {
            int n = n0 + jj;
            float kv = smem[tok * 132 + n];
            float vv = smem[tok * 132 + 64 + n];
            orow[jj] = f2bf(__expf(-__expf(tf[n]) * kv) * vv);
        }
    }
}

// ---------------- scan: per-chunk local -> carries (FALLBACK path only) -----
__global__ __launch_bounds__(64) void k_chunk(const short* __restrict__ wkvb,
                                              const float* __restrict__ tdec,
                                              float* __restrict__ Acar) {
    int idx = blockIdx.x;
    int n = threadIdx.x;
    float w = expf(tdec[n]);
    const short* p = wkvb + (size_t)idx * (LCH * N_) + n;
    float s = 0.f;
#pragma unroll
    for (int i = 0; i < LCH; i++) s = s * w + bf2f(p[i * N_]);
    Acar[idx * N_ + n] = s;
}

// ---------------- scan: carries across chunks; write last_states -----------
__global__ __launch_bounds__(64) void k_carry(const float* __restrict__ Acar,
                                              const float* __restrict__ tdec,
                                              float* __restrict__ Cin,
                                              float* __restrict__ last) {
    int b = blockIdx.x;
    int n = threadIdx.x;
    float wL = expf(tdec[n] * (float)LCH);
    float c = 0.f;
#pragma unroll 16
    for (int ch = 0; ch < CCH; ch++) {
        Cin[(b * CCH + ch) * N_ + n] = c;
        c = c * wL + Acar[(b * CCH + ch) * N_ + n];
    }
    last[b * N_ + n] = c;
}

// ---------------- output projection, rescan FUSED in (bf16 wkv) -------------
__global__ __launch_bounds__(256) void k_out_mx(const short* __restrict__ wkvb,
                                                const float* __restrict__ Cin,
                                                const float* __restrict__ tdec,
                                                const short* __restrict__ owbf,
                                                float* __restrict__ out) {
    __shared__ __align__(16) char smem[64 * 132 * 4];   // 33.8 KB
    char* stl = smem;               // phase-1 view: [64 rows][128 B] swizzled bf16
    float* C = (float*)smem;        // phase-2 view

    int tid = threadIdx.x, wid = tid >> 6, lane = tid & 63;
    int wm = wid >> 1, wn = wid & 1;
    int quad = lane >> 4, l15 = lane & 15;
    int m0 = (blockIdx.x >> 1) * 64;
    int dh = blockIdx.x & 1;        // d-half: 0 -> d 0..511, 1 -> 512..1023

    // ---- phase 1: rescan 2 chunks into swizzled LDS bf16 tile ----
    if (tid < 128) {
        int c = tid >> 6, n = tid & 63;
        int idx = (blockIdx.x >> 1) * 2 + c;           // global chunk index
        float w = expf(tdec[n]);                       // matches k_carry/k_chunk
        float s = Cin[idx * N_ + n];
        const short* p = wkvb + (size_t)idx * (LCH * N_) + n;
        int cu = (n * 2) >> 4, off = (n * 2) & 15;     // 16B unit + byte within
#pragma unroll
        for (int i = 0; i < LCH; i++) {
            s = s * w + bf2f(p[i * N_]);
            int row = c * 32 + i;
            *(short*)(stl + row * 128 + ((cu ^ (row & 7)) << 4) + off) = f2bf(s);
        }
    }
    __syncthreads();   // st tile ready

    // ---- A fragments once into registers (swizzled LDS read) ----
    v8s a[2][2];
#pragma unroll
    for (int i = 0; i < 2; i++)
#pragma unroll
        for (int ks = 0; ks < 2; ks++) {
            int row = wm * 32 + i * 16 + l15;
            int cu = quad + ks * 4;                    // col = quad*8 + ks*32 bf16
            a[i][ks] = *(const v8s*)(stl + row * 128 + ((cu ^ (row & 7)) << 4));
        }

    int rrow = tid >> 3;
    int ccol = (tid & 7) * 4;

    for (int dt = 0; dt < 4; ++dt) {
        int d0 = (dh * 4 + dt) * 128;
        const short* bb = owbf + ((size_t)(d0 + wn * 64 + l15)) * N_ + quad * 8;
        v4f acc[2][4];
#pragma unroll
        for (int i = 0; i < 2; i++)
#pragma unroll
            for (int j = 0; j < 4; j++) acc[i][j] = (v4f)0.f;
#pragma unroll
        for (int ks = 0; ks < 2; ks++) {
            v8s b0 = *(const v8s*)(bb + ks * 32);
            v8s b1 = *(const v8s*)(bb + 16 * N_ + ks * 32);
            v8s b2 = *(const v8s*)(bb + 32 * N_ + ks * 32);
            v8s b3 = *(const v8s*)(bb + 48 * N_ + ks * 32);
            acc[0][0] = __builtin_amdgcn_mfma_f32_16x16x32_bf16(a[0][ks], b0, acc[0][0], 0, 0, 0);
            acc[0][1] = __builtin_amdgcn_mfma_f32_16x16x32_bf16(a[0][ks], b1, acc[0][1], 0, 0, 0);
            acc[0][2] = __builtin_amdgcn_mfma_f32_16x16x32_bf16(a[0][ks], b2, acc[0][2], 0, 0, 0);
            acc[0][3] = __builtin_amdgcn_mfma_f32_16x16x32_bf16(a[0][ks], b3, acc[0][3], 0, 0, 0);
            acc[1][0] = __builtin_amdgcn_mfma_f32_16x16x32_bf16(a[1][ks], b0, acc[1][0], 0, 0, 0);
            acc[1][1] = __builtin_amdgcn_mfma_f32_16x16x32_bf16(a[1][ks], b1, acc[1][1], 0, 0, 0);
            acc[1][2] = __builtin_amdgcn_mfma_f32_16x16x32_bf16(a[1][ks], b2, acc[1][2], 0, 0, 0);
            acc[1][3] = __builtin_amdgcn_mfma_f32_16x16x32_bf16(a[1][ks], b3, acc[1][3], 0, 0, 0);
        }
        __syncthreads();   // dt=0: all A-frag reads done (st death);
                           // dt>0: previous iteration's C-reads done
        // stash C in LDS (same proven layout)
#pragma unroll
        for (int i = 0; i < 2; i++)
#pragma unroll
            for (int j = 0; j < 4; j++)
#pragma unroll
                for (int r = 0; r < 4; r++)
                    C[(wm * 32 + i * 16 + quad * 4 + r) * 132 + wn * 64 + j * 16 + l15] = acc[i][j][r];
        __syncthreads();   // C fully written
        // coalesced stores: 8 lanes cover one row's 128B segment per instruction
#pragma unroll
        for (int rep = 0; rep < 2; rep++) {
            int row = rep * 32 + rrow;
            float* orow = out + ((size_t)(m0 + row)) * D_ + d0;
            const float* crow = &C[row * 132];
#pragma unroll
            for (int k = 0; k < 4; k++) {
                int col = ccol + k * 32;
                *(float4*)(orow + col) = *(const float4*)(crow + col);
            }
        }
    }
}

extern "C" void kernel_launch(void* const* d_in, const int* in_sizes, int n_in,
                              void* d_out, int out_size, void* d_ws, size_t ws_size,
                              hipStream_t stream) {
    const float* x    = (const float*)d_in[0];
    const float* tdec = (const float*)d_in[1];
    const float* tf   = (const float*)d_in[2];
    const float* keyw = (const float*)d_in[3];
    const float* valw = (const float*)d_in[4];
    const float* ow   = (const float*)d_in[5];
    const float* tsg  = (const float*)d_in[6];
    const float* lnw  = (const float*)d_in[7];
    const float* lnb  = (const float*)d_in[8];
    float* out = (float*)d_out;
    float* ws  = (float*)d_ws;

    // workspace layout (float offsets; wkv slot kept at legacy size)
    float* g     = ws;                        // 1024
    float* etf   = g + 1024;                  // 64
    short* wbf   = (short*)(etf + 64);        // 131072 shorts = 65536 floats
    short* owbf  = (short*)(ws + 66624);      // 65536 shorts = 32768 floats
    float* mu    = ws + 99392;                // 32768
    float* rstd  = mu + 32768;                // 32768
    float* wkvs  = rstd + 32768;              // legacy 2097152-float slot
    short* wkvb  = (short*)wkvs;              // bf16 wkv lives in its front half
    float* Acar  = wkvs + 2097152;            // 65536
    float* Cin   = Acar + 65536;              // 65536
    short* xnorm = (short*)(ws + 3441728);    // 33554432 shorts = 16777216 floats
    const size_t NEED_PRIMARY = (size_t)(3441728 + 16777216) * 4;  // ~80.9 MB

    if (ws_size >= NEED_PRIMARY) {
        // conv merged into the stats launch (blocks >= 16384 do conv work)
        k_stats_conv<<<16384 + 773, 256, 0, stream>>>(
            x, tsg, lnw, lnb, xnorm, keyw, valw, ow, tf, wbf, owbf, etf, g);
        // proj also emits Acar (chunk carries) -> no k_chunk in this path
        k_proj_mx<<<MTOT / 64, 256, 0, stream>>>(xnorm, wbf, etf, tdec, wkvb, Acar);
    } else {
        k_conv<<<773, 256, 0, stream>>>(keyw, valw, ow, tf, tsg, wbf, owbf, etf, g);
        k_stats_mu<<<B_ * (S_ / 2), 256, 0, stream>>>(x, g, mu, rstd);
        k_proj_fp32<<<MTOT / 64, 256, 0, stream>>>(x, keyw, valw, g, lnw, lnb, tf, mu, rstd, wkvb);
        k_chunk <<<B_ * CCH, 64, 0, stream>>>(wkvb, tdec, Acar);
    }
    k_carry <<<B_, 64, 0, stream>>>(Acar, tdec, Cin, out + (size_t)MTOT * D_);
    // rescan is fused into k_out_mx (reads bf16 wkv + Cin; no stbf buffer)
    k_out_mx<<<(MTOT / 64) * 2, 256, 0, stream>>>(wkvb, Cin, tdec, owbf, out);
}